// Round 1
// baseline (2982.390 us; speedup 1.0000x reference)
//
#include <hip/hip_runtime.h>
#include <math.h>

#define N_NODES 100000
#define N_EDGES 1600000
#define D 64
#define DOUT 40

// ---------------------------------------------------------------------------
// Edge aggregation: 16 threads per edge, each handles 4 contiguous floats.
// Gather x[src] (float4) -> atomicAdd into agg[dst]. Lane 0 of the 16-group
// bumps deg[dst] when deg != nullptr (first layer only).
// ---------------------------------------------------------------------------
__global__ __launch_bounds__(256) void edge_agg_kernel(
    const float* __restrict__ x, const int* __restrict__ src,
    const int* __restrict__ dst, float* __restrict__ agg,
    float* __restrict__ deg, int E) {
  int gid = blockIdx.x * blockDim.x + threadIdx.x;
  int part = gid & 15;                 // which 4-float chunk of the 64-dim row
  int e = gid >> 4;
  int estride = (gridDim.x * blockDim.x) >> 4;
  for (; e < E; e += estride) {
    int s = src[e];
    int d = dst[e];
    float4 v = *reinterpret_cast<const float4*>(x + (size_t)s * D + part * 4);
    float* a = agg + (size_t)d * D + part * 4;
    atomicAdd(a + 0, v.x);
    atomicAdd(a + 1, v.y);
    atomicAdd(a + 2, v.z);
    atomicAdd(a + 3, v.w);
    if (deg && part == 0) atomicAdd(deg + d, 1.0f);
  }
}

// ---------------------------------------------------------------------------
// Layer 1: h = relu( (agg/deg) @ W1l^T + b1 + x @ W1r^T )
// One wave per node; lane t computes output feature t.
// Weights staged in LDS with +1 padding => bank (lane + k) % 32, conflict-free.
// xs/ms are wave-local LDS broadcast buffers (no cross-wave sharing, so no
// __syncthreads needed inside the node loop).
// ---------------------------------------------------------------------------
__global__ __launch_bounds__(256) void layer1_kernel(
    const float* __restrict__ x, const float* __restrict__ agg,
    const float* __restrict__ deg, const float* __restrict__ W1l,
    const float* __restrict__ b1, const float* __restrict__ W1r,
    float* __restrict__ h, int N) {
  __shared__ float Wl[D][D + 1];
  __shared__ float Wr[D][D + 1];
  __shared__ float xs[4][D];
  __shared__ float ms[4][D];
  for (int i = threadIdx.x; i < D * D; i += 256) {
    int r = i >> 6, c = i & (D - 1);
    Wl[r][c] = W1l[i];
    Wr[r][c] = W1r[i];
  }
  __syncthreads();
  int wave = threadIdx.x >> 6;
  int lane = threadIdx.x & 63;
  float bias = b1[lane];
  int wid = blockIdx.x * 4 + wave;
  int nw = gridDim.x * 4;
  for (int node = wid; node < N; node += nw) {
    float inv = 1.0f / fmaxf(deg[node], 1.0f);
    xs[wave][lane] = x[(size_t)node * D + lane];
    ms[wave][lane] = agg[(size_t)node * D + lane] * inv;
    float acc = bias;
#pragma unroll
    for (int k = 0; k < D; ++k)
      acc += ms[wave][k] * Wl[lane][k] + xs[wave][k] * Wr[lane][k];
    h[(size_t)node * D + lane] = fmaxf(acc, 0.0f);
  }
}

// ---------------------------------------------------------------------------
// Layer 2: o = (agg2/deg) @ W2l^T + b2 + h @ W2r^T ; out = log_softmax(o)
// One wave per node; lanes 0..39 hold the 40 outputs; full-wave shuffle
// reduction for max and sum(exp).
// ---------------------------------------------------------------------------
__global__ __launch_bounds__(256) void layer2_kernel(
    const float* __restrict__ h, const float* __restrict__ agg,
    const float* __restrict__ deg, const float* __restrict__ W2l,
    const float* __restrict__ b2, const float* __restrict__ W2r,
    float* __restrict__ out, int N) {
  __shared__ float Wl[DOUT][D + 1];
  __shared__ float Wr[DOUT][D + 1];
  __shared__ float hs[4][D];
  __shared__ float ms[4][D];
  for (int i = threadIdx.x; i < DOUT * D; i += 256) {
    int r = i >> 6, c = i & (D - 1);
    Wl[r][c] = W2l[i];
    Wr[r][c] = W2r[i];
  }
  __syncthreads();
  int wave = threadIdx.x >> 6;
  int lane = threadIdx.x & 63;
  float bias = (lane < DOUT) ? b2[lane] : 0.0f;
  int wid = blockIdx.x * 4 + wave;
  int nw = gridDim.x * 4;
  for (int node = wid; node < N; node += nw) {
    float inv = 1.0f / fmaxf(deg[node], 1.0f);
    hs[wave][lane] = h[(size_t)node * D + lane];
    ms[wave][lane] = agg[(size_t)node * D + lane] * inv;
    float acc = bias;
    if (lane < DOUT) {
#pragma unroll
      for (int k = 0; k < D; ++k)
        acc += ms[wave][k] * Wl[lane][k] + hs[wave][k] * Wr[lane][k];
    }
    float v = (lane < DOUT) ? acc : -INFINITY;
    float mx = v;
    for (int off = 32; off; off >>= 1) mx = fmaxf(mx, __shfl_xor(mx, off, 64));
    float ex = (lane < DOUT) ? expf(acc - mx) : 0.0f;
    float sm = ex;
    for (int off = 32; off; off >>= 1) sm += __shfl_xor(sm, off, 64);
    if (lane < DOUT) out[(size_t)node * DOUT + lane] = acc - mx - logf(sm);
  }
}

extern "C" void kernel_launch(void* const* d_in, const int* in_sizes, int n_in,
                              void* d_out, int out_size, void* d_ws, size_t ws_size,
                              hipStream_t stream) {
  const float* x   = (const float*)d_in[0];
  const int*   ei  = (const int*)d_in[1];   // [2, E] int32 (harness-converted)
  const float* W1l = (const float*)d_in[2];
  const float* b1  = (const float*)d_in[3];
  const float* W1r = (const float*)d_in[4];
  const float* W2l = (const float*)d_in[5];
  const float* b2  = (const float*)d_in[6];
  const float* W2r = (const float*)d_in[7];
  float* out = (float*)d_out;

  const int* src = ei;
  const int* dst = ei + N_EDGES;

  char* ws = (char*)d_ws;
  size_t aggB = (size_t)N_NODES * D * sizeof(float);   // 25.6 MB
  size_t degB = (size_t)N_NODES * sizeof(float);       // 0.4 MB
  float* agg = (float*)ws;
  float* deg = (float*)(ws + aggB);
  float* h   = (float*)(ws + aggB + degB);             // 16B-aligned offset

  // ---- layer 1 ----
  hipMemsetAsync(agg, 0, aggB + degB, stream);         // zero agg + deg
  edge_agg_kernel<<<4096, 256, 0, stream>>>(x, src, dst, agg, deg, N_EDGES);
  layer1_kernel<<<1024, 256, 0, stream>>>(x, agg, deg, W1l, b1, W1r, h, N_NODES);

  // ---- layer 2 ----
  hipMemsetAsync(agg, 0, aggB, stream);                // re-zero agg only
  edge_agg_kernel<<<4096, 256, 0, stream>>>(h, src, dst, agg, nullptr, N_EDGES);
  layer2_kernel<<<1024, 256, 0, stream>>>(h, agg, deg, W2l, b2, W2r, out, N_NODES);
}

// Round 2
// 851.836 us; speedup vs baseline: 3.5011x; 3.5011x over previous
//
#include <hip/hip_runtime.h>
#include <math.h>

#define N_NODES 100000
#define N_EDGES 1600000
#define D 64
#define DOUT 40

// ---------------------------------------------------------------------------
// Pass 1: degree histogram (int atomics, 1.6M x 4B — L2-resident)
// ---------------------------------------------------------------------------
__global__ __launch_bounds__(256) void hist_kernel(const int* __restrict__ dst,
                                                   int* __restrict__ deg, int E) {
  int e = blockIdx.x * 256 + threadIdx.x;
  if (e < E) atomicAdd(&deg[dst[e]], 1);
}

// ---------------------------------------------------------------------------
// Pass 2: exclusive prefix-sum of deg -> row_start (and cursor copy).
// Single block, 1024 threads; thread t serially sums its contiguous chunk,
// Hillis-Steele block scan of the 1024 chunk sums, then writes prefixes.
// ---------------------------------------------------------------------------
__global__ __launch_bounds__(1024) void scan_kernel(const int* __restrict__ deg,
                                                    int* __restrict__ row_start,
                                                    int* __restrict__ cursor, int N) {
  __shared__ int sums[1024];
  const int CHUNK = (N + 1023) / 1024;
  int t = threadIdx.x;
  int begin = t * CHUNK;
  int end = min(begin + CHUNK, N);
  int s = 0;
  for (int i = begin; i < end; ++i) s += deg[i];
  sums[t] = s;
  __syncthreads();
  for (int off = 1; off < 1024; off <<= 1) {
    int v = (t >= off) ? sums[t - off] : 0;
    __syncthreads();
    sums[t] += v;
    __syncthreads();
  }
  int run = (t == 0) ? 0 : sums[t - 1];
  for (int i = begin; i < end; ++i) {
    row_start[i] = run;
    cursor[i] = run;
    run += deg[i];
  }
  if (t == 1023) row_start[N] = run;
}

// ---------------------------------------------------------------------------
// Pass 3: scatter edges into CSR (order within a node irrelevant for sum)
// ---------------------------------------------------------------------------
__global__ __launch_bounds__(256) void scatter_kernel(const int* __restrict__ src,
                                                      const int* __restrict__ dst,
                                                      int* __restrict__ cursor,
                                                      int* __restrict__ csr, int E) {
  int e = blockIdx.x * 256 + threadIdx.x;
  if (e < E) {
    int p = atomicAdd(&cursor[dst[e]], 1);
    csr[p] = src[e];
  }
}

// ---------------------------------------------------------------------------
// Layer 1 fused: gather-mean (register accumulate, no atomics) + linear + ReLU
// One wave per node; lane = feature. Neighbor ids loaded 64-wide then
// broadcast via __shfl; each edge costs one coalesced 256B row read (L2/L3).
// ---------------------------------------------------------------------------
__global__ __launch_bounds__(256) void sage1_kernel(
    const float* __restrict__ x, const int* __restrict__ row_start,
    const int* __restrict__ csr, const float* __restrict__ W1l,
    const float* __restrict__ b1, const float* __restrict__ W1r,
    float* __restrict__ h, int N) {
  __shared__ float Wl[D][D + 1];
  __shared__ float Wr[D][D + 1];
  __shared__ float ms[4][D];
  __shared__ float xs[4][D];
  for (int i = threadIdx.x; i < D * D; i += 256) {
    int r = i >> 6, c = i & 63;
    Wl[r][c] = W1l[i];
    Wr[r][c] = W1r[i];
  }
  __syncthreads();
  int wave = threadIdx.x >> 6;
  int lane = threadIdx.x & 63;
  float bias = b1[lane];
  int wid = blockIdx.x * 4 + wave;
  int nw = gridDim.x * 4;
  for (int node = wid; node < N; node += nw) {
    int rs = row_start[node];
    int re = row_start[node + 1];
    float acc = 0.0f;
    for (int base = rs; base < re; base += 64) {
      int rem = re - base;
      int cnt = rem < 64 ? rem : 64;
      int idx = (lane < cnt) ? csr[base + lane] : 0;
      for (int j = 0; j < cnt; ++j) {
        int s = __shfl(idx, j, 64);
        acc += x[(size_t)s * D + lane];
      }
    }
    float mean = acc / fmaxf((float)(re - rs), 1.0f);
    ms[wave][lane] = mean;
    xs[wave][lane] = x[(size_t)node * D + lane];
    float o = bias;
#pragma unroll 16
    for (int k = 0; k < D; ++k)
      o += ms[wave][k] * Wl[lane][k] + xs[wave][k] * Wr[lane][k];
    h[(size_t)node * D + lane] = fmaxf(o, 0.0f);
  }
}

// ---------------------------------------------------------------------------
// Layer 2 fused: gather-mean + linear + log_softmax
// ---------------------------------------------------------------------------
__global__ __launch_bounds__(256) void sage2_kernel(
    const float* __restrict__ h, const int* __restrict__ row_start,
    const int* __restrict__ csr, const float* __restrict__ W2l,
    const float* __restrict__ b2, const float* __restrict__ W2r,
    float* __restrict__ out, int N) {
  __shared__ float Wl[DOUT][D + 1];
  __shared__ float Wr[DOUT][D + 1];
  __shared__ float hs[4][D];
  __shared__ float ms[4][D];
  for (int i = threadIdx.x; i < DOUT * D; i += 256) {
    int r = i >> 6, c = i & 63;
    Wl[r][c] = W2l[i];
    Wr[r][c] = W2r[i];
  }
  __syncthreads();
  int wave = threadIdx.x >> 6;
  int lane = threadIdx.x & 63;
  float bias = (lane < DOUT) ? b2[lane] : 0.0f;
  int wid = blockIdx.x * 4 + wave;
  int nw = gridDim.x * 4;
  for (int node = wid; node < N; node += nw) {
    int rs = row_start[node];
    int re = row_start[node + 1];
    float acc = 0.0f;
    for (int base = rs; base < re; base += 64) {
      int rem = re - base;
      int cnt = rem < 64 ? rem : 64;
      int idx = (lane < cnt) ? csr[base + lane] : 0;
      for (int j = 0; j < cnt; ++j) {
        int s = __shfl(idx, j, 64);
        acc += h[(size_t)s * D + lane];
      }
    }
    float mean = acc / fmaxf((float)(re - rs), 1.0f);
    ms[wave][lane] = mean;
    hs[wave][lane] = h[(size_t)node * D + lane];
    float o = bias;
    if (lane < DOUT) {
#pragma unroll 16
      for (int k = 0; k < D; ++k)
        o += ms[wave][k] * Wl[lane][k] + hs[wave][k] * Wr[lane][k];
    }
    float v = (lane < DOUT) ? o : -INFINITY;
    float mx = v;
    for (int off = 32; off; off >>= 1) mx = fmaxf(mx, __shfl_xor(mx, off, 64));
    float ex = (lane < DOUT) ? expf(o - mx) : 0.0f;
    float sm = ex;
    for (int off = 32; off; off >>= 1) sm += __shfl_xor(sm, off, 64);
    if (lane < DOUT) out[(size_t)node * DOUT + lane] = o - mx - logf(sm);
  }
}

extern "C" void kernel_launch(void* const* d_in, const int* in_sizes, int n_in,
                              void* d_out, int out_size, void* d_ws, size_t ws_size,
                              hipStream_t stream) {
  const float* x   = (const float*)d_in[0];
  const int*   ei  = (const int*)d_in[1];
  const float* W1l = (const float*)d_in[2];
  const float* b1  = (const float*)d_in[3];
  const float* W1r = (const float*)d_in[4];
  const float* W2l = (const float*)d_in[5];
  const float* b2  = (const float*)d_in[6];
  const float* W2r = (const float*)d_in[7];
  float* out = (float*)d_out;

  const int* src = ei;
  const int* dst = ei + N_EDGES;

  char* ws = (char*)d_ws;
  float* h        = (float*)ws;                               // 25.6 MB
  int*   deg      = (int*)(ws + (size_t)N_NODES * D * 4);     // 400 KB
  int*   row_start= deg + N_NODES;                            // 400 KB (+1)
  int*   cursor   = row_start + N_NODES + 1;                  // 400 KB
  int*   csr      = cursor + N_NODES;                         // 6.4 MB

  // ---- build CSR ----
  hipMemsetAsync(deg, 0, (size_t)N_NODES * sizeof(int), stream);
  hist_kernel<<<(N_EDGES + 255) / 256, 256, 0, stream>>>(dst, deg, N_EDGES);
  scan_kernel<<<1, 1024, 0, stream>>>(deg, row_start, cursor, N_NODES);
  scatter_kernel<<<(N_EDGES + 255) / 256, 256, 0, stream>>>(src, dst, cursor, csr, N_EDGES);

  // ---- fused layers ----
  sage1_kernel<<<2048, 256, 0, stream>>>(x, row_start, csr, W1l, b1, W1r, h, N_NODES);
  sage2_kernel<<<2048, 256, 0, stream>>>(h, row_start, csr, W2l, b2, W2r, out, N_NODES);
}

// Round 3
// 672.902 us; speedup vs baseline: 4.4321x; 1.2659x over previous
//
#include <hip/hip_runtime.h>
#include <math.h>

#define N_NODES 100000
#define N_EDGES 1600000
#define D 64
#define DW 68   // padded weight row (16B-aligned, bank-spread)
#define DOUT 40

// ---------------------------------------------------------------------------
// Pass 1: degree histogram
// ---------------------------------------------------------------------------
__global__ __launch_bounds__(256) void hist_kernel(const int* __restrict__ dst,
                                                   int* __restrict__ deg, int E) {
  int e = blockIdx.x * 256 + threadIdx.x;
  if (e < E) atomicAdd(&deg[dst[e]], 1);
}

// ---------------------------------------------------------------------------
// Pass 2: exclusive prefix-sum of deg -> row_start (+cursor copy)
// ---------------------------------------------------------------------------
__global__ __launch_bounds__(1024) void scan_kernel(const int* __restrict__ deg,
                                                    int* __restrict__ row_start,
                                                    int* __restrict__ cursor, int N) {
  __shared__ int sums[1024];
  const int CHUNK = (N + 1023) / 1024;
  int t = threadIdx.x;
  int begin = t * CHUNK;
  int end = min(begin + CHUNK, N);
  int s = 0;
  for (int i = begin; i < end; ++i) s += deg[i];
  sums[t] = s;
  __syncthreads();
  for (int off = 1; off < 1024; off <<= 1) {
    int v = (t >= off) ? sums[t - off] : 0;
    __syncthreads();
    sums[t] += v;
    __syncthreads();
  }
  int run = (t == 0) ? 0 : sums[t - 1];
  for (int i = begin; i < end; ++i) {
    row_start[i] = run;
    cursor[i] = run;
    run += deg[i];
  }
  if (t == 1023) row_start[N] = run;
}

// ---------------------------------------------------------------------------
// Pass 3: scatter edges into CSR
// ---------------------------------------------------------------------------
__global__ __launch_bounds__(256) void scatter_kernel(const int* __restrict__ src,
                                                      const int* __restrict__ dst,
                                                      int* __restrict__ cursor,
                                                      int* __restrict__ csr, int E) {
  int e = blockIdx.x * 256 + threadIdx.x;
  if (e < E) {
    int p = atomicAdd(&cursor[dst[e]], 1);
    csr[p] = src[e];
  }
}

// ---------------------------------------------------------------------------
// Layer 1 fused. Wave = 4 groups x 16 lanes. Group g handles one edge at a
// time; lane t of the group loads float4 chunk t (16B) of the source row.
// Unroll x2 => 8 independent 16B loads in flight per lane-pair per iter.
// Butterfly shfl_xor(16,32) folds group partials -> full 64-dim mean.
// Linear: lane = out feature, float4 LDS reads, weight rows padded to 68.
// ---------------------------------------------------------------------------
__global__ __launch_bounds__(256) void sage1_kernel(
    const float* __restrict__ x, const int* __restrict__ row_start,
    const int* __restrict__ csr, const float* __restrict__ W1l,
    const float* __restrict__ b1, const float* __restrict__ W1r,
    float* __restrict__ h, int N) {
  __shared__ float Wl[D][DW];
  __shared__ float Wr[D][DW];
  __shared__ float ms[4][D];
  __shared__ float xs[4][D];
  for (int i = threadIdx.x; i < D * D; i += 256) {
    int r = i >> 6, c = i & 63;
    Wl[r][c] = W1l[i];
    Wr[r][c] = W1r[i];
  }
  __syncthreads();
  int wave = threadIdx.x >> 6;
  int lane = threadIdx.x & 63;
  int g = lane >> 4;        // edge group 0..3
  int t = lane & 15;        // float4 chunk 0..15
  float bias = b1[lane];
  int wid = blockIdx.x * 4 + wave;
  int nw = gridDim.x * 4;
  for (int node = wid; node < N; node += nw) {
    int rs = row_start[node];
    int re = row_start[node + 1];
    float4 acc = make_float4(0.f, 0.f, 0.f, 0.f);
    int e = rs + g;
    for (; e + 4 < re; e += 8) {
      int s0 = csr[e];
      int s1 = csr[e + 4];
      float4 v0 = *reinterpret_cast<const float4*>(x + (size_t)s0 * D + t * 4);
      float4 v1 = *reinterpret_cast<const float4*>(x + (size_t)s1 * D + t * 4);
      acc.x += v0.x + v1.x; acc.y += v0.y + v1.y;
      acc.z += v0.z + v1.z; acc.w += v0.w + v1.w;
    }
    if (e < re) {
      int s0 = csr[e];
      float4 v0 = *reinterpret_cast<const float4*>(x + (size_t)s0 * D + t * 4);
      acc.x += v0.x; acc.y += v0.y; acc.z += v0.z; acc.w += v0.w;
    }
    // fold 4 group partials (lanes t, t+16, t+32, t+48)
    acc.x += __shfl_xor(acc.x, 16, 64); acc.y += __shfl_xor(acc.y, 16, 64);
    acc.z += __shfl_xor(acc.z, 16, 64); acc.w += __shfl_xor(acc.w, 16, 64);
    acc.x += __shfl_xor(acc.x, 32, 64); acc.y += __shfl_xor(acc.y, 32, 64);
    acc.z += __shfl_xor(acc.z, 32, 64); acc.w += __shfl_xor(acc.w, 32, 64);
    float inv = 1.0f / fmaxf((float)(re - rs), 1.0f);
    if (g == 0) {
      float4 m4 = make_float4(acc.x * inv, acc.y * inv, acc.z * inv, acc.w * inv);
      *reinterpret_cast<float4*>(&ms[wave][t * 4]) = m4;
    }
    xs[wave][lane] = x[(size_t)node * D + lane];
    float o = bias;
#pragma unroll
    for (int k = 0; k < D; k += 4) {
      float4 m = *reinterpret_cast<const float4*>(&ms[wave][k]);
      float4 xv = *reinterpret_cast<const float4*>(&xs[wave][k]);
      float4 wl = *reinterpret_cast<const float4*>(&Wl[lane][k]);
      float4 wr = *reinterpret_cast<const float4*>(&Wr[lane][k]);
      o += m.x * wl.x + m.y * wl.y + m.z * wl.z + m.w * wl.w;
      o += xv.x * wr.x + xv.y * wr.y + xv.z * wr.z + xv.w * wr.w;
    }
    h[(size_t)node * D + lane] = fmaxf(o, 0.0f);
  }
}

// ---------------------------------------------------------------------------
// Layer 2 fused: same gather structure + 40-wide linear + log_softmax
// ---------------------------------------------------------------------------
__global__ __launch_bounds__(256) void sage2_kernel(
    const float* __restrict__ h, const int* __restrict__ row_start,
    const int* __restrict__ csr, const float* __restrict__ W2l,
    const float* __restrict__ b2, const float* __restrict__ W2r,
    float* __restrict__ out, int N) {
  __shared__ float Wl[DOUT][DW];
  __shared__ float Wr[DOUT][DW];
  __shared__ float hs[4][D];
  __shared__ float ms[4][D];
  for (int i = threadIdx.x; i < DOUT * D; i += 256) {
    int r = i >> 6, c = i & 63;
    Wl[r][c] = W2l[i];
    Wr[r][c] = W2r[i];
  }
  __syncthreads();
  int wave = threadIdx.x >> 6;
  int lane = threadIdx.x & 63;
  int g = lane >> 4;
  int t = lane & 15;
  float bias = (lane < DOUT) ? b2[lane] : 0.0f;
  int wid = blockIdx.x * 4 + wave;
  int nw = gridDim.x * 4;
  for (int node = wid; node < N; node += nw) {
    int rs = row_start[node];
    int re = row_start[node + 1];
    float4 acc = make_float4(0.f, 0.f, 0.f, 0.f);
    int e = rs + g;
    for (; e + 4 < re; e += 8) {
      int s0 = csr[e];
      int s1 = csr[e + 4];
      float4 v0 = *reinterpret_cast<const float4*>(h + (size_t)s0 * D + t * 4);
      float4 v1 = *reinterpret_cast<const float4*>(h + (size_t)s1 * D + t * 4);
      acc.x += v0.x + v1.x; acc.y += v0.y + v1.y;
      acc.z += v0.z + v1.z; acc.w += v0.w + v1.w;
    }
    if (e < re) {
      int s0 = csr[e];
      float4 v0 = *reinterpret_cast<const float4*>(h + (size_t)s0 * D + t * 4);
      acc.x += v0.x; acc.y += v0.y; acc.z += v0.z; acc.w += v0.w;
    }
    acc.x += __shfl_xor(acc.x, 16, 64); acc.y += __shfl_xor(acc.y, 16, 64);
    acc.z += __shfl_xor(acc.z, 16, 64); acc.w += __shfl_xor(acc.w, 16, 64);
    acc.x += __shfl_xor(acc.x, 32, 64); acc.y += __shfl_xor(acc.y, 32, 64);
    acc.z += __shfl_xor(acc.z, 32, 64); acc.w += __shfl_xor(acc.w, 32, 64);
    float inv = 1.0f / fmaxf((float)(re - rs), 1.0f);
    if (g == 0) {
      float4 m4 = make_float4(acc.x * inv, acc.y * inv, acc.z * inv, acc.w * inv);
      *reinterpret_cast<float4*>(&ms[wave][t * 4]) = m4;
    }
    hs[wave][lane] = h[(size_t)node * D + lane];
    float o = bias;
    if (lane < DOUT) {
#pragma unroll
      for (int k = 0; k < D; k += 4) {
        float4 m = *reinterpret_cast<const float4*>(&ms[wave][k]);
        float4 hv = *reinterpret_cast<const float4*>(&hs[wave][k]);
        float4 wl = *reinterpret_cast<const float4*>(&Wl[lane][k]);
        float4 wr = *reinterpret_cast<const float4*>(&Wr[lane][k]);
        o += m.x * wl.x + m.y * wl.y + m.z * wl.z + m.w * wl.w;
        o += hv.x * wr.x + hv.y * wr.y + hv.z * wr.z + hv.w * wr.w;
      }
    }
    float v = (lane < DOUT) ? o : -INFINITY;
    float mx = v;
    for (int off = 32; off; off >>= 1) mx = fmaxf(mx, __shfl_xor(mx, off, 64));
    float ex = (lane < DOUT) ? expf(o - mx) : 0.0f;
    float sm = ex;
    for (int off = 32; off; off >>= 1) sm += __shfl_xor(sm, off, 64);
    if (lane < DOUT) out[(size_t)node * DOUT + lane] = o - mx - logf(sm);
  }
}

extern "C" void kernel_launch(void* const* d_in, const int* in_sizes, int n_in,
                              void* d_out, int out_size, void* d_ws, size_t ws_size,
                              hipStream_t stream) {
  const float* x   = (const float*)d_in[0];
  const int*   ei  = (const int*)d_in[1];
  const float* W1l = (const float*)d_in[2];
  const float* b1  = (const float*)d_in[3];
  const float* W1r = (const float*)d_in[4];
  const float* W2l = (const float*)d_in[5];
  const float* b2  = (const float*)d_in[6];
  const float* W2r = (const float*)d_in[7];
  float* out = (float*)d_out;

  const int* src = ei;
  const int* dst = ei + N_EDGES;

  char* ws = (char*)d_ws;
  float* h        = (float*)ws;                               // 25.6 MB
  int*   deg      = (int*)(ws + (size_t)N_NODES * D * 4);     // 400 KB
  int*   row_start= deg + N_NODES;                            // 400 KB (+1)
  int*   cursor   = row_start + N_NODES + 1;                  // 400 KB
  int*   csr      = cursor + N_NODES;                         // 6.4 MB

  // ---- build CSR ----
  hipMemsetAsync(deg, 0, (size_t)N_NODES * sizeof(int), stream);
  hist_kernel<<<(N_EDGES + 255) / 256, 256, 0, stream>>>(dst, deg, N_EDGES);
  scan_kernel<<<1, 1024, 0, stream>>>(deg, row_start, cursor, N_NODES);
  scatter_kernel<<<(N_EDGES + 255) / 256, 256, 0, stream>>>(src, dst, cursor, csr, N_EDGES);

  // ---- fused layers ----
  sage1_kernel<<<2048, 256, 0, stream>>>(x, row_start, csr, W1l, b1, W1r, h, N_NODES);
  sage2_kernel<<<2048, 256, 0, stream>>>(h, row_start, csr, W2l, b2, W2r, out, N_NODES);
}

// Round 4
// 448.023 us; speedup vs baseline: 6.6568x; 1.5019x over previous
//
#include <hip/hip_runtime.h>
#include <math.h>

#define N_NODES 100000
#define N_EDGES 1600000
#define D 64
#define DW 68   // padded weight row (16B-aligned, bank-spread)
#define DOUT 40

// ---------------------------------------------------------------------------
// Pass 1: degree histogram
// ---------------------------------------------------------------------------
__global__ __launch_bounds__(256) void hist_kernel(const int* __restrict__ dst,
                                                   int* __restrict__ deg, int E) {
  int e = blockIdx.x * 256 + threadIdx.x;
  if (e < E) atomicAdd(&deg[dst[e]], 1);
}

// ---------------------------------------------------------------------------
// Pass 2a: per-block (1024-wide) exclusive scan of deg -> row_start,
//          block total -> bsum[blockIdx]
// ---------------------------------------------------------------------------
__global__ __launch_bounds__(1024) void scan_a_kernel(const int* __restrict__ deg,
                                                      int* __restrict__ row_start,
                                                      int* __restrict__ bsum, int N) {
  __shared__ int s[1024];
  int t = threadIdx.x;
  int i = blockIdx.x * 1024 + t;
  int v = (i < N) ? deg[i] : 0;
  s[t] = v;
  __syncthreads();
  for (int off = 1; off < 1024; off <<= 1) {
    int u = (t >= off) ? s[t - off] : 0;
    __syncthreads();
    s[t] += u;
    __syncthreads();
  }
  if (i < N) row_start[i] = s[t] - v;   // exclusive prefix within block
  if (t == 1023) bsum[blockIdx.x] = s[1023];
}

// ---------------------------------------------------------------------------
// Pass 2b: exclusive scan of the (<=128) block sums, in place
// ---------------------------------------------------------------------------
__global__ __launch_bounds__(128) void scan_b_kernel(int* __restrict__ bsum, int nb) {
  __shared__ int s[128];
  int t = threadIdx.x;
  int v = (t < nb) ? bsum[t] : 0;
  s[t] = v;
  __syncthreads();
  for (int off = 1; off < 128; off <<= 1) {
    int u = (t >= off) ? s[t - off] : 0;
    __syncthreads();
    s[t] += u;
    __syncthreads();
  }
  if (t < nb) bsum[t] = s[t] - v;       // exclusive
}

// ---------------------------------------------------------------------------
// Pass 2c: add block offsets, copy to cursor, set sentinel
// ---------------------------------------------------------------------------
__global__ __launch_bounds__(256) void scan_c_kernel(int* __restrict__ row_start,
                                                     int* __restrict__ cursor,
                                                     const int* __restrict__ bsum,
                                                     int N, int E) {
  int i = blockIdx.x * 256 + threadIdx.x;
  if (i < N) {
    int v = row_start[i] + bsum[i >> 10];
    row_start[i] = v;
    cursor[i] = v;
  }
  if (i == 0) row_start[N] = E;
}

// ---------------------------------------------------------------------------
// Pass 3: scatter edges into CSR
// ---------------------------------------------------------------------------
__global__ __launch_bounds__(256) void scatter_kernel(const int* __restrict__ src,
                                                      const int* __restrict__ dst,
                                                      int* __restrict__ cursor,
                                                      int* __restrict__ csr, int E) {
  int e = blockIdx.x * 256 + threadIdx.x;
  if (e < E) {
    int p = atomicAdd(&cursor[dst[e]], 1);
    csr[p] = src[e];
  }
}

// ---------------------------------------------------------------------------
// Layer 1 fused. Wave = 4 groups x 16 lanes; group g owns one edge, lane t
// loads float4 chunk t of the source row. Unroll x2 for load concurrency.
// Butterfly shfl_xor(16,32) folds group partials -> full 64-dim mean.
// ---------------------------------------------------------------------------
__global__ __launch_bounds__(256) void sage1_kernel(
    const float* __restrict__ x, const int* __restrict__ row_start,
    const int* __restrict__ csr, const float* __restrict__ W1l,
    const float* __restrict__ b1, const float* __restrict__ W1r,
    float* __restrict__ h, int N) {
  __shared__ float Wl[D][DW];
  __shared__ float Wr[D][DW];
  __shared__ float ms[4][D];
  __shared__ float xs[4][D];
  for (int i = threadIdx.x; i < D * D; i += 256) {
    int r = i >> 6, c = i & 63;
    Wl[r][c] = W1l[i];
    Wr[r][c] = W1r[i];
  }
  __syncthreads();
  int wave = threadIdx.x >> 6;
  int lane = threadIdx.x & 63;
  int g = lane >> 4;        // edge group 0..3
  int t = lane & 15;        // float4 chunk 0..15
  float bias = b1[lane];
  int wid = blockIdx.x * 4 + wave;
  int nw = gridDim.x * 4;
  for (int node = wid; node < N; node += nw) {
    int rs = row_start[node];
    int re = row_start[node + 1];
    float4 acc = make_float4(0.f, 0.f, 0.f, 0.f);
    int e = rs + g;
    for (; e + 4 < re; e += 8) {
      int s0 = csr[e];
      int s1 = csr[e + 4];
      float4 v0 = *reinterpret_cast<const float4*>(x + (size_t)s0 * D + t * 4);
      float4 v1 = *reinterpret_cast<const float4*>(x + (size_t)s1 * D + t * 4);
      acc.x += v0.x + v1.x; acc.y += v0.y + v1.y;
      acc.z += v0.z + v1.z; acc.w += v0.w + v1.w;
    }
    if (e < re) {
      int s0 = csr[e];
      float4 v0 = *reinterpret_cast<const float4*>(x + (size_t)s0 * D + t * 4);
      acc.x += v0.x; acc.y += v0.y; acc.z += v0.z; acc.w += v0.w;
    }
    acc.x += __shfl_xor(acc.x, 16, 64); acc.y += __shfl_xor(acc.y, 16, 64);
    acc.z += __shfl_xor(acc.z, 16, 64); acc.w += __shfl_xor(acc.w, 16, 64);
    acc.x += __shfl_xor(acc.x, 32, 64); acc.y += __shfl_xor(acc.y, 32, 64);
    acc.z += __shfl_xor(acc.z, 32, 64); acc.w += __shfl_xor(acc.w, 32, 64);
    float inv = 1.0f / fmaxf((float)(re - rs), 1.0f);
    if (g == 0) {
      float4 m4 = make_float4(acc.x * inv, acc.y * inv, acc.z * inv, acc.w * inv);
      *reinterpret_cast<float4*>(&ms[wave][t * 4]) = m4;
    }
    xs[wave][lane] = x[(size_t)node * D + lane];
    float o = bias;
#pragma unroll
    for (int k = 0; k < D; k += 4) {
      float4 m = *reinterpret_cast<const float4*>(&ms[wave][k]);
      float4 xv = *reinterpret_cast<const float4*>(&xs[wave][k]);
      float4 wl = *reinterpret_cast<const float4*>(&Wl[lane][k]);
      float4 wr = *reinterpret_cast<const float4*>(&Wr[lane][k]);
      o += m.x * wl.x + m.y * wl.y + m.z * wl.z + m.w * wl.w;
      o += xv.x * wr.x + xv.y * wr.y + xv.z * wr.z + xv.w * wr.w;
    }
    h[(size_t)node * D + lane] = fmaxf(o, 0.0f);
  }
}

// ---------------------------------------------------------------------------
// Layer 2 fused: same gather structure + 40-wide linear + log_softmax
// ---------------------------------------------------------------------------
__global__ __launch_bounds__(256) void sage2_kernel(
    const float* __restrict__ h, const int* __restrict__ row_start,
    const int* __restrict__ csr, const float* __restrict__ W2l,
    const float* __restrict__ b2, const float* __restrict__ W2r,
    float* __restrict__ out, int N) {
  __shared__ float Wl[DOUT][DW];
  __shared__ float Wr[DOUT][DW];
  __shared__ float hs[4][D];
  __shared__ float ms[4][D];
  for (int i = threadIdx.x; i < DOUT * D; i += 256) {
    int r = i >> 6, c = i & 63;
    Wl[r][c] = W2l[i];
    Wr[r][c] = W2r[i];
  }
  __syncthreads();
  int wave = threadIdx.x >> 6;
  int lane = threadIdx.x & 63;
  int g = lane >> 4;
  int t = lane & 15;
  float bias = (lane < DOUT) ? b2[lane] : 0.0f;
  int wid = blockIdx.x * 4 + wave;
  int nw = gridDim.x * 4;
  for (int node = wid; node < N; node += nw) {
    int rs = row_start[node];
    int re = row_start[node + 1];
    float4 acc = make_float4(0.f, 0.f, 0.f, 0.f);
    int e = rs + g;
    for (; e + 4 < re; e += 8) {
      int s0 = csr[e];
      int s1 = csr[e + 4];
      float4 v0 = *reinterpret_cast<const float4*>(h + (size_t)s0 * D + t * 4);
      float4 v1 = *reinterpret_cast<const float4*>(h + (size_t)s1 * D + t * 4);
      acc.x += v0.x + v1.x; acc.y += v0.y + v1.y;
      acc.z += v0.z + v1.z; acc.w += v0.w + v1.w;
    }
    if (e < re) {
      int s0 = csr[e];
      float4 v0 = *reinterpret_cast<const float4*>(h + (size_t)s0 * D + t * 4);
      acc.x += v0.x; acc.y += v0.y; acc.z += v0.z; acc.w += v0.w;
    }
    acc.x += __shfl_xor(acc.x, 16, 64); acc.y += __shfl_xor(acc.y, 16, 64);
    acc.z += __shfl_xor(acc.z, 16, 64); acc.w += __shfl_xor(acc.w, 16, 64);
    acc.x += __shfl_xor(acc.x, 32, 64); acc.y += __shfl_xor(acc.y, 32, 64);
    acc.z += __shfl_xor(acc.z, 32, 64); acc.w += __shfl_xor(acc.w, 32, 64);
    float inv = 1.0f / fmaxf((float)(re - rs), 1.0f);
    if (g == 0) {
      float4 m4 = make_float4(acc.x * inv, acc.y * inv, acc.z * inv, acc.w * inv);
      *reinterpret_cast<float4*>(&ms[wave][t * 4]) = m4;
    }
    hs[wave][lane] = h[(size_t)node * D + lane];
    float o = bias;
    if (lane < DOUT) {
#pragma unroll
      for (int k = 0; k < D; k += 4) {
        float4 m = *reinterpret_cast<const float4*>(&ms[wave][k]);
        float4 hv = *reinterpret_cast<const float4*>(&hs[wave][k]);
        float4 wl = *reinterpret_cast<const float4*>(&Wl[lane][k]);
        float4 wr = *reinterpret_cast<const float4*>(&Wr[lane][k]);
        o += m.x * wl.x + m.y * wl.y + m.z * wl.z + m.w * wl.w;
        o += hv.x * wr.x + hv.y * wr.y + hv.z * wr.z + hv.w * wr.w;
      }
    }
    float v = (lane < DOUT) ? o : -INFINITY;
    float mx = v;
    for (int off = 32; off; off >>= 1) mx = fmaxf(mx, __shfl_xor(mx, off, 64));
    float ex = (lane < DOUT) ? expf(o - mx) : 0.0f;
    float sm = ex;
    for (int off = 32; off; off >>= 1) sm += __shfl_xor(sm, off, 64);
    if (lane < DOUT) out[(size_t)node * DOUT + lane] = o - mx - logf(sm);
  }
}

extern "C" void kernel_launch(void* const* d_in, const int* in_sizes, int n_in,
                              void* d_out, int out_size, void* d_ws, size_t ws_size,
                              hipStream_t stream) {
  const float* x   = (const float*)d_in[0];
  const int*   ei  = (const int*)d_in[1];
  const float* W1l = (const float*)d_in[2];
  const float* b1  = (const float*)d_in[3];
  const float* W1r = (const float*)d_in[4];
  const float* W2l = (const float*)d_in[5];
  const float* b2  = (const float*)d_in[6];
  const float* W2r = (const float*)d_in[7];
  float* out = (float*)d_out;

  const int* src = ei;
  const int* dst = ei + N_EDGES;

  char* ws = (char*)d_ws;
  float* h        = (float*)ws;                               // 25.6 MB
  int*   deg      = (int*)(ws + (size_t)N_NODES * D * 4);     // 400 KB
  int*   row_start= deg + N_NODES;                            // 400 KB (+1)
  int*   cursor   = row_start + N_NODES + 1;                  // 400 KB
  int*   csr      = cursor + N_NODES;                         // 6.4 MB
  int*   bsum     = csr + N_EDGES;                            // 512 B

  const int NB = (N_NODES + 1023) / 1024;   // 98 scan blocks

  // ---- build CSR ----
  hipMemsetAsync(deg, 0, (size_t)N_NODES * sizeof(int), stream);
  hist_kernel<<<(N_EDGES + 255) / 256, 256, 0, stream>>>(dst, deg, N_EDGES);
  scan_a_kernel<<<NB, 1024, 0, stream>>>(deg, row_start, bsum, N_NODES);
  scan_b_kernel<<<1, 128, 0, stream>>>(bsum, NB);
  scan_c_kernel<<<(N_NODES + 255) / 256, 256, 0, stream>>>(row_start, cursor, bsum,
                                                           N_NODES, N_EDGES);
  scatter_kernel<<<(N_EDGES + 255) / 256, 256, 0, stream>>>(src, dst, cursor, csr, N_EDGES);

  // ---- fused layers ----
  sage1_kernel<<<2048, 256, 0, stream>>>(x, row_start, csr, W1l, b1, W1r, h, N_NODES);
  sage2_kernel<<<2048, 256, 0, stream>>>(h, row_start, csr, W2l, b2, W2r, out, N_NODES);
}

// Round 5
// 432.337 us; speedup vs baseline: 6.8983x; 1.0363x over previous
//
#include <hip/hip_runtime.h>
#include <math.h>

#define N_NODES 100000
#define N_EDGES 1600000
#define D 64
#define DW 68   // padded f32 weight row (16B-aligned)
#define DOUT 40

__device__ inline float bf2f(unsigned u) {
  union { unsigned i; float f; } v;
  v.i = u << 16;
  return v.f;
}
__device__ inline unsigned f2bf(float f) {
  union { float f; unsigned i; } v;
  v.f = f;
  unsigned r = v.i + 0x7fffu + ((v.i >> 16) & 1u);   // RNE
  return r >> 16;
}
__device__ inline void addrow(float* acc, uint4 r) {
  acc[0] += bf2f(r.x & 0xffffu); acc[1] += bf2f(r.x >> 16);
  acc[2] += bf2f(r.y & 0xffffu); acc[3] += bf2f(r.y >> 16);
  acc[4] += bf2f(r.z & 0xffffu); acc[5] += bf2f(r.z >> 16);
  acc[6] += bf2f(r.w & 0xffffu); acc[7] += bf2f(r.w >> 16);
}

// ---------------------------------------------------------------------------
// f32 -> bf16 convert (8 floats / thread)
// ---------------------------------------------------------------------------
__global__ __launch_bounds__(256) void cvt_kernel(const float* __restrict__ in,
                                                  unsigned short* __restrict__ ob,
                                                  int n8) {
  int i = blockIdx.x * 256 + threadIdx.x;
  if (i >= n8) return;
  const float4* p = reinterpret_cast<const float4*>(in) + (size_t)i * 2;
  float4 a = p[0], b = p[1];
  uint4 o;
  o.x = f2bf(a.x) | (f2bf(a.y) << 16);
  o.y = f2bf(a.z) | (f2bf(a.w) << 16);
  o.z = f2bf(b.x) | (f2bf(b.y) << 16);
  o.w = f2bf(b.z) | (f2bf(b.w) << 16);
  reinterpret_cast<uint4*>(ob)[i] = o;
}

// ---------------------------------------------------------------------------
// CSR build: histogram, 3-phase scan, scatter
// ---------------------------------------------------------------------------
__global__ __launch_bounds__(256) void hist_kernel(const int* __restrict__ dst,
                                                   int* __restrict__ deg, int E) {
  int e = blockIdx.x * 256 + threadIdx.x;
  if (e < E) atomicAdd(&deg[dst[e]], 1);
}

__global__ __launch_bounds__(1024) void scan_a_kernel(const int* __restrict__ deg,
                                                      int* __restrict__ row_start,
                                                      int* __restrict__ bsum, int N) {
  __shared__ int s[1024];
  int t = threadIdx.x;
  int i = blockIdx.x * 1024 + t;
  int v = (i < N) ? deg[i] : 0;
  s[t] = v;
  __syncthreads();
  for (int off = 1; off < 1024; off <<= 1) {
    int u = (t >= off) ? s[t - off] : 0;
    __syncthreads();
    s[t] += u;
    __syncthreads();
  }
  if (i < N) row_start[i] = s[t] - v;
  if (t == 1023) bsum[blockIdx.x] = s[1023];
}

__global__ __launch_bounds__(128) void scan_b_kernel(int* __restrict__ bsum, int nb) {
  __shared__ int s[128];
  int t = threadIdx.x;
  int v = (t < nb) ? bsum[t] : 0;
  s[t] = v;
  __syncthreads();
  for (int off = 1; off < 128; off <<= 1) {
    int u = (t >= off) ? s[t - off] : 0;
    __syncthreads();
    s[t] += u;
    __syncthreads();
  }
  if (t < nb) bsum[t] = s[t] - v;
}

__global__ __launch_bounds__(256) void scan_c_kernel(int* __restrict__ row_start,
                                                     int* __restrict__ cursor,
                                                     const int* __restrict__ bsum,
                                                     int N, int E) {
  int i = blockIdx.x * 256 + threadIdx.x;
  if (i < N) {
    int v = row_start[i] + bsum[i >> 10];
    row_start[i] = v;
    cursor[i] = v;
  }
  if (i == 0) row_start[N] = E;
}

__global__ __launch_bounds__(256) void scatter_kernel(const int* __restrict__ src,
                                                      const int* __restrict__ dst,
                                                      int* __restrict__ cursor,
                                                      int* __restrict__ csr, int E) {
  int e = blockIdx.x * 256 + threadIdx.x;
  if (e < E) {
    int p = atomicAdd(&cursor[dst[e]], 1);
    csr[p] = src[e];
  }
}

// ---------------------------------------------------------------------------
// Layer 1 fused. Wave = 8 groups x 8 lanes; group g owns one edge, lane t
// loads uint4 = 8 bf16 features (16B) of the 128B source row. Unroll x2 =>
// 16 edges / wave-iter. Fold via shfl_xor(8,16,32). Self term from f32 x.
// Output h written as bf16.
// ---------------------------------------------------------------------------
__global__ __launch_bounds__(256) void sage1_kernel(
    const float* __restrict__ x, const unsigned short* __restrict__ xbf,
    const int* __restrict__ row_start, const int* __restrict__ csr,
    const float* __restrict__ W1l, const float* __restrict__ b1,
    const float* __restrict__ W1r, unsigned short* __restrict__ hbf, int N) {
  __shared__ float Wl[D][DW];
  __shared__ float Wr[D][DW];
  __shared__ float ms[4][D];
  __shared__ float xs[4][D];
  for (int i = threadIdx.x; i < D * D; i += 256) {
    int r = i >> 6, c = i & 63;
    Wl[r][c] = W1l[i];
    Wr[r][c] = W1r[i];
  }
  __syncthreads();
  int wave = threadIdx.x >> 6;
  int lane = threadIdx.x & 63;
  int g = lane >> 3;        // edge group 0..7
  int t = lane & 7;         // 8-feature chunk 0..7
  float bias = b1[lane];
  int wid = blockIdx.x * 4 + wave;
  int nw = gridDim.x * 4;
  for (int node = wid; node < N; node += nw) {
    int rs = row_start[node];
    int re = row_start[node + 1];
    float acc[8] = {0.f, 0.f, 0.f, 0.f, 0.f, 0.f, 0.f, 0.f};
    int e = rs + g;
    for (; e + 8 < re; e += 16) {
      int s0 = csr[e];
      int s1 = csr[e + 8];
      uint4 r0 = *reinterpret_cast<const uint4*>(xbf + (size_t)s0 * D + t * 8);
      uint4 r1 = *reinterpret_cast<const uint4*>(xbf + (size_t)s1 * D + t * 8);
      addrow(acc, r0);
      addrow(acc, r1);
    }
    if (e < re) {
      int s0 = csr[e];
      uint4 r0 = *reinterpret_cast<const uint4*>(xbf + (size_t)s0 * D + t * 8);
      addrow(acc, r0);
    }
#pragma unroll
    for (int j = 0; j < 8; ++j) {
      acc[j] += __shfl_xor(acc[j], 8, 64);
      acc[j] += __shfl_xor(acc[j], 16, 64);
      acc[j] += __shfl_xor(acc[j], 32, 64);
    }
    float inv = 1.0f / fmaxf((float)(re - rs), 1.0f);
    if (g == 0) {
      float4 m0 = make_float4(acc[0] * inv, acc[1] * inv, acc[2] * inv, acc[3] * inv);
      float4 m1 = make_float4(acc[4] * inv, acc[5] * inv, acc[6] * inv, acc[7] * inv);
      *reinterpret_cast<float4*>(&ms[wave][t * 8]) = m0;
      *reinterpret_cast<float4*>(&ms[wave][t * 8 + 4]) = m1;
    }
    xs[wave][lane] = x[(size_t)node * D + lane];
    float o = bias;
#pragma unroll
    for (int k = 0; k < D; k += 4) {
      float4 m = *reinterpret_cast<const float4*>(&ms[wave][k]);
      float4 xv = *reinterpret_cast<const float4*>(&xs[wave][k]);
      float4 wl = *reinterpret_cast<const float4*>(&Wl[lane][k]);
      float4 wr = *reinterpret_cast<const float4*>(&Wr[lane][k]);
      o += m.x * wl.x + m.y * wl.y + m.z * wl.z + m.w * wl.w;
      o += xv.x * wr.x + xv.y * wr.y + xv.z * wr.z + xv.w * wr.w;
    }
    hbf[(size_t)node * D + lane] = (unsigned short)f2bf(fmaxf(o, 0.0f));
  }
}

// ---------------------------------------------------------------------------
// Layer 2 fused: bf16 gather + 40-wide linear + log_softmax
// ---------------------------------------------------------------------------
__global__ __launch_bounds__(256) void sage2_kernel(
    const unsigned short* __restrict__ hbf, const int* __restrict__ row_start,
    const int* __restrict__ csr, const float* __restrict__ W2l,
    const float* __restrict__ b2, const float* __restrict__ W2r,
    float* __restrict__ out, int N) {
  __shared__ float Wl[DOUT][DW];
  __shared__ float Wr[DOUT][DW];
  __shared__ float hs[4][D];
  __shared__ float ms[4][D];
  for (int i = threadIdx.x; i < DOUT * D; i += 256) {
    int r = i >> 6, c = i & 63;
    Wl[r][c] = W2l[i];
    Wr[r][c] = W2r[i];
  }
  __syncthreads();
  int wave = threadIdx.x >> 6;
  int lane = threadIdx.x & 63;
  int g = lane >> 3;
  int t = lane & 7;
  float bias = (lane < DOUT) ? b2[lane] : 0.0f;
  int wid = blockIdx.x * 4 + wave;
  int nw = gridDim.x * 4;
  for (int node = wid; node < N; node += nw) {
    int rs = row_start[node];
    int re = row_start[node + 1];
    float acc[8] = {0.f, 0.f, 0.f, 0.f, 0.f, 0.f, 0.f, 0.f};
    int e = rs + g;
    for (; e + 8 < re; e += 16) {
      int s0 = csr[e];
      int s1 = csr[e + 8];
      uint4 r0 = *reinterpret_cast<const uint4*>(hbf + (size_t)s0 * D + t * 8);
      uint4 r1 = *reinterpret_cast<const uint4*>(hbf + (size_t)s1 * D + t * 8);
      addrow(acc, r0);
      addrow(acc, r1);
    }
    if (e < re) {
      int s0 = csr[e];
      uint4 r0 = *reinterpret_cast<const uint4*>(hbf + (size_t)s0 * D + t * 8);
      addrow(acc, r0);
    }
#pragma unroll
    for (int j = 0; j < 8; ++j) {
      acc[j] += __shfl_xor(acc[j], 8, 64);
      acc[j] += __shfl_xor(acc[j], 16, 64);
      acc[j] += __shfl_xor(acc[j], 32, 64);
    }
    float inv = 1.0f / fmaxf((float)(re - rs), 1.0f);
    if (g == 0) {
      float4 m0 = make_float4(acc[0] * inv, acc[1] * inv, acc[2] * inv, acc[3] * inv);
      float4 m1 = make_float4(acc[4] * inv, acc[5] * inv, acc[6] * inv, acc[7] * inv);
      *reinterpret_cast<float4*>(&ms[wave][t * 8]) = m0;
      *reinterpret_cast<float4*>(&ms[wave][t * 8 + 4]) = m1;
    }
    hs[wave][lane] = bf2f(hbf[(size_t)node * D + lane]);
    float o = bias;
    if (lane < DOUT) {
#pragma unroll
      for (int k = 0; k < D; k += 4) {
        float4 m = *reinterpret_cast<const float4*>(&ms[wave][k]);
        float4 hv = *reinterpret_cast<const float4*>(&hs[wave][k]);
        float4 wl = *reinterpret_cast<const float4*>(&Wl[lane][k]);
        float4 wr = *reinterpret_cast<const float4*>(&Wr[lane][k]);
        o += m.x * wl.x + m.y * wl.y + m.z * wl.z + m.w * wl.w;
        o += hv.x * wr.x + hv.y * wr.y + hv.z * wr.z + hv.w * wr.w;
      }
    }
    float v = (lane < DOUT) ? o : -INFINITY;
    float mx = v;
    for (int off = 32; off; off >>= 1) mx = fmaxf(mx, __shfl_xor(mx, off, 64));
    float ex = (lane < DOUT) ? expf(o - mx) : 0.0f;
    float sm = ex;
    for (int off = 32; off; off >>= 1) sm += __shfl_xor(sm, off, 64);
    if (lane < DOUT) out[(size_t)node * DOUT + lane] = o - mx - logf(sm);
  }
}

extern "C" void kernel_launch(void* const* d_in, const int* in_sizes, int n_in,
                              void* d_out, int out_size, void* d_ws, size_t ws_size,
                              hipStream_t stream) {
  const float* x   = (const float*)d_in[0];
  const int*   ei  = (const int*)d_in[1];
  const float* W1l = (const float*)d_in[2];
  const float* b1  = (const float*)d_in[3];
  const float* W1r = (const float*)d_in[4];
  const float* W2l = (const float*)d_in[5];
  const float* b2  = (const float*)d_in[6];
  const float* W2r = (const float*)d_in[7];
  float* out = (float*)d_out;

  const int* src = ei;
  const int* dst = ei + N_EDGES;

  char* ws = (char*)d_ws;
  size_t featB = (size_t)N_NODES * D * sizeof(unsigned short);  // 12.8 MB
  unsigned short* xbf = (unsigned short*)ws;
  unsigned short* hbf = (unsigned short*)(ws + featB);
  int* deg       = (int*)(ws + 2 * featB);                      // 400 KB
  int* row_start = deg + N_NODES;                               // 400 KB (+1)
  int* cursor    = row_start + N_NODES + 1;                     // 400 KB
  int* csr       = cursor + N_NODES;                            // 6.4 MB
  int* bsum      = csr + N_EDGES;                               // 512 B

  const int NB = (N_NODES + 1023) / 1024;

  // ---- bf16 feature cache (independent of CSR chain) ----
  cvt_kernel<<<(N_NODES * D / 8 + 255) / 256, 256, 0, stream>>>(x, xbf, N_NODES * D / 8);

  // ---- build CSR ----
  hipMemsetAsync(deg, 0, (size_t)N_NODES * sizeof(int), stream);
  hist_kernel<<<(N_EDGES + 255) / 256, 256, 0, stream>>>(dst, deg, N_EDGES);
  scan_a_kernel<<<NB, 1024, 0, stream>>>(deg, row_start, bsum, N_NODES);
  scan_b_kernel<<<1, 128, 0, stream>>>(bsum, NB);
  scan_c_kernel<<<(N_NODES + 255) / 256, 256, 0, stream>>>(row_start, cursor, bsum,
                                                           N_NODES, N_EDGES);
  scatter_kernel<<<(N_EDGES + 255) / 256, 256, 0, stream>>>(src, dst, cursor, csr, N_EDGES);

  // ---- fused layers ----
  sage1_kernel<<<2048, 256, 0, stream>>>(x, xbf, row_start, csr, W1l, b1, W1r, hbf, N_NODES);
  sage2_kernel<<<2048, 256, 0, stream>>>(hbf, row_start, csr, W2l, b2, W2r, out, N_NODES);
}

// Round 6
// 292.445 us; speedup vs baseline: 10.1981x; 1.4784x over previous
//
#include <hip/hip_runtime.h>
#include <math.h>

#define N_NODES 100000
#define N_EDGES 1600000
#define D 64
#define DW 68   // padded f32 weight row (16B-aligned)
#define DOUT 40
#define NBUCK ((N_NODES + 255) / 256)   // 391 coarse buckets of 256 dst-nodes

__device__ inline float bf2f(unsigned u) {
  union { unsigned i; float f; } v;
  v.i = u << 16;
  return v.f;
}
__device__ inline unsigned f2bf(float f) {
  union { float f; unsigned i; } v;
  v.f = f;
  unsigned r = v.i + 0x7fffu + ((v.i >> 16) & 1u);   // RNE
  return r >> 16;
}
__device__ inline void addrow(float* acc, uint4 r) {
  acc[0] += bf2f(r.x & 0xffffu); acc[1] += bf2f(r.x >> 16);
  acc[2] += bf2f(r.y & 0xffffu); acc[3] += bf2f(r.y >> 16);
  acc[4] += bf2f(r.z & 0xffffu); acc[5] += bf2f(r.z >> 16);
  acc[6] += bf2f(r.w & 0xffffu); acc[7] += bf2f(r.w >> 16);
}

// ---------------------------------------------------------------------------
// f32 -> bf16 convert (8 floats / thread)
// ---------------------------------------------------------------------------
__global__ __launch_bounds__(256) void cvt_kernel(const float* __restrict__ in,
                                                  unsigned short* __restrict__ ob,
                                                  int n8) {
  int i = blockIdx.x * 256 + threadIdx.x;
  if (i >= n8) return;
  const float4* p = reinterpret_cast<const float4*>(in) + (size_t)i * 2;
  float4 a = p[0], b = p[1];
  uint4 o;
  o.x = f2bf(a.x) | (f2bf(a.y) << 16);
  o.y = f2bf(a.z) | (f2bf(a.w) << 16);
  o.z = f2bf(b.x) | (f2bf(b.y) << 16);
  o.w = f2bf(b.z) | (f2bf(b.w) << 16);
  reinterpret_cast<uint4*>(ob)[i] = o;
}

// ---------------------------------------------------------------------------
// CSR build v2: two-level bucket sort (write-locality-aware)
// bucket(d) = d >> 8 ; entry = (dstLocal << 24) | src  (src < 2^24)
// ---------------------------------------------------------------------------
// Pass 1: coarse bucket histogram via LDS, 391 global atomics per block
__global__ __launch_bounds__(256) void bhist_kernel(const int* __restrict__ dst,
                                                    int* __restrict__ bcnt, int E) {
  __shared__ int c[512];
  int t = threadIdx.x;
  c[t] = 0; c[t + 256] = 0;
  __syncthreads();
  int cbase = blockIdx.x * 4096;
  int cc = min(4096, E - cbase);
  for (int i = t; i < cc; i += 256) atomicAdd(&c[dst[cbase + i] >> 8], 1);
  __syncthreads();
  for (int b = t; b < NBUCK; b += 256)
    if (c[b]) atomicAdd(&bcnt[b], c[b]);
}

// Pass 2: exclusive scan of bucket counts -> bstart (+sentinel), bcursor
__global__ __launch_bounds__(256) void bscan_kernel(const int* __restrict__ bcnt,
                                                    int* __restrict__ bstart,
                                                    int* __restrict__ bcursor, int E) {
  __shared__ int s[512];
  int t = threadIdx.x;
  int o0 = (t < NBUCK) ? bcnt[t] : 0;
  int o1 = (t + 256 < NBUCK) ? bcnt[t + 256] : 0;
  s[t] = o0; s[t + 256] = o1;
  __syncthreads();
  for (int off = 1; off < 512; off <<= 1) {
    int v0 = (t >= off) ? s[t - off] : 0;
    int v1 = s[t + 256 - off];
    __syncthreads();
    s[t] += v0; s[t + 256] += v1;
    __syncthreads();
  }
  if (t < NBUCK) { bstart[t] = s[t] - o0; bcursor[t] = s[t] - o0; }
  if (t + 256 < NBUCK) { bstart[t + 256] = s[t + 256] - o1; bcursor[t + 256] = s[t + 256] - o1; }
  if (t == 0) bstart[NBUCK] = E;
}

// Pass 3: chunked LDS counting-sort by bucket, contiguous run writes
__global__ __launch_bounds__(256) void bscatter_kernel(const int* __restrict__ src,
                                                       const int* __restrict__ dst,
                                                       int* __restrict__ bcursor,
                                                       unsigned* __restrict__ binned,
                                                       int E) {
  __shared__ unsigned ent[4096];
  __shared__ unsigned short sbk[4096];
  __shared__ int cnt[512], scn[512], pos[512], base[512];
  int t = threadIdx.x;
  int cbase = blockIdx.x * 4096;
  int cc = min(4096, E - cbase);
  cnt[t] = 0; cnt[t + 256] = 0;
  __syncthreads();
  unsigned my_e[16];
  int my_b[16];
  int nmine = 0;
#pragma unroll
  for (int i = 0; i < 16; ++i) {
    int li = t + i * 256;
    if (li < cc) {
      int s = src[cbase + li];
      int d = dst[cbase + li];
      int b = d >> 8;
      my_e[nmine] = ((unsigned)(d & 255) << 24) | (unsigned)s;
      my_b[nmine] = b;
      nmine++;
      atomicAdd(&cnt[b], 1);
    }
  }
  __syncthreads();
  scn[t] = cnt[t]; scn[t + 256] = cnt[t + 256];
  __syncthreads();
  for (int off = 1; off < 512; off <<= 1) {
    int v0 = (t >= off) ? scn[t - off] : 0;
    int v1 = scn[t + 256 - off];
    __syncthreads();
    scn[t] += v0; scn[t + 256] += v1;
    __syncthreads();
  }
  pos[t] = scn[t] - cnt[t];
  pos[t + 256] = scn[t + 256] - cnt[t + 256];
  __syncthreads();
  for (int i = 0; i < nmine; ++i) {
    int slot = atomicAdd(&pos[my_b[i]], 1);
    ent[slot] = my_e[i];
    sbk[slot] = (unsigned short)my_b[i];
  }
  __syncthreads();
  for (int b = t; b < NBUCK; b += 256)
    if (cnt[b] > 0) base[b] = atomicAdd(&bcursor[b], cnt[b]);
  __syncthreads();
  for (int i = t; i < cc; i += 256) {
    int b = sbk[i];
    int excl = scn[b] - cnt[b];
    binned[base[b] + (i - excl)] = ent[i];
  }
}

// Pass 4: per-bucket fine counting-sort -> csr + row_start (coalesced writes)
__global__ __launch_bounds__(256) void bfine_kernel(const unsigned* __restrict__ binned,
                                                    const int* __restrict__ bstart,
                                                    int* __restrict__ row_start,
                                                    int* __restrict__ csr, int N, int E) {
  __shared__ int c[256], p[256], pos[256];
  int b = blockIdx.x;
  int t = threadIdx.x;
  int s0 = bstart[b], s1 = bstart[b + 1];
  c[t] = 0;
  __syncthreads();
  for (int i = s0 + t; i < s1; i += 256)
    atomicAdd(&c[binned[i] >> 24], 1);
  __syncthreads();
  p[t] = c[t];
  __syncthreads();
  for (int off = 1; off < 256; off <<= 1) {
    int v = (t >= off) ? p[t - off] : 0;
    __syncthreads();
    p[t] += v;
    __syncthreads();
  }
  int excl = p[t] - c[t];
  int node = b * 256 + t;
  if (node < N) row_start[node] = s0 + excl;
  if (b == 0 && t == 0) row_start[N] = E;
  pos[t] = excl;
  __syncthreads();
  for (int i = s0 + t; i < s1; i += 256) {
    unsigned u = binned[i];
    int slot = atomicAdd(&pos[u >> 24], 1);
    csr[s0 + slot] = (int)(u & 0xFFFFFFu);
  }
}

// ---------------------------------------------------------------------------
// Layer 1 fused. Wave = 8 groups x 8 lanes; group g owns one edge, lane t
// loads uint4 = 8 bf16 features (16B). Unroll x2 => 16 edges/wave-iter.
// ---------------------------------------------------------------------------
__global__ __launch_bounds__(256) void sage1_kernel(
    const float* __restrict__ x, const unsigned short* __restrict__ xbf,
    const int* __restrict__ row_start, const int* __restrict__ csr,
    const float* __restrict__ W1l, const float* __restrict__ b1,
    const float* __restrict__ W1r, unsigned short* __restrict__ hbf, int N) {
  __shared__ float Wl[D][DW];
  __shared__ float Wr[D][DW];
  __shared__ float ms[4][D];
  __shared__ float xs[4][D];
  for (int i = threadIdx.x; i < D * D; i += 256) {
    int r = i >> 6, c = i & 63;
    Wl[r][c] = W1l[i];
    Wr[r][c] = W1r[i];
  }
  __syncthreads();
  int wave = threadIdx.x >> 6;
  int lane = threadIdx.x & 63;
  int g = lane >> 3;
  int t = lane & 7;
  float bias = b1[lane];
  int wid = blockIdx.x * 4 + wave;
  int nw = gridDim.x * 4;
  for (int node = wid; node < N; node += nw) {
    int rs = row_start[node];
    int re = row_start[node + 1];
    float acc[8] = {0.f, 0.f, 0.f, 0.f, 0.f, 0.f, 0.f, 0.f};
    int e = rs + g;
    for (; e + 8 < re; e += 16) {
      int s0 = csr[e];
      int s1 = csr[e + 8];
      uint4 r0 = *reinterpret_cast<const uint4*>(xbf + (size_t)s0 * D + t * 8);
      uint4 r1 = *reinterpret_cast<const uint4*>(xbf + (size_t)s1 * D + t * 8);
      addrow(acc, r0);
      addrow(acc, r1);
    }
    if (e < re) {
      int s0 = csr[e];
      uint4 r0 = *reinterpret_cast<const uint4*>(xbf + (size_t)s0 * D + t * 8);
      addrow(acc, r0);
    }
#pragma unroll
    for (int j = 0; j < 8; ++j) {
      acc[j] += __shfl_xor(acc[j], 8, 64);
      acc[j] += __shfl_xor(acc[j], 16, 64);
      acc[j] += __shfl_xor(acc[j], 32, 64);
    }
    float inv = 1.0f / fmaxf((float)(re - rs), 1.0f);
    if (g == 0) {
      float4 m0 = make_float4(acc[0] * inv, acc[1] * inv, acc[2] * inv, acc[3] * inv);
      float4 m1 = make_float4(acc[4] * inv, acc[5] * inv, acc[6] * inv, acc[7] * inv);
      *reinterpret_cast<float4*>(&ms[wave][t * 8]) = m0;
      *reinterpret_cast<float4*>(&ms[wave][t * 8 + 4]) = m1;
    }
    xs[wave][lane] = x[(size_t)node * D + lane];
    float o = bias;
#pragma unroll
    for (int k = 0; k < D; k += 4) {
      float4 m = *reinterpret_cast<const float4*>(&ms[wave][k]);
      float4 xv = *reinterpret_cast<const float4*>(&xs[wave][k]);
      float4 wl = *reinterpret_cast<const float4*>(&Wl[lane][k]);
      float4 wr = *reinterpret_cast<const float4*>(&Wr[lane][k]);
      o += m.x * wl.x + m.y * wl.y + m.z * wl.z + m.w * wl.w;
      o += xv.x * wr.x + xv.y * wr.y + xv.z * wr.z + xv.w * wr.w;
    }
    hbf[(size_t)node * D + lane] = (unsigned short)f2bf(fmaxf(o, 0.0f));
  }
}

// ---------------------------------------------------------------------------
// Layer 2 fused: bf16 gather + 40-wide linear + log_softmax
// ---------------------------------------------------------------------------
__global__ __launch_bounds__(256) void sage2_kernel(
    const unsigned short* __restrict__ hbf, const int* __restrict__ row_start,
    const int* __restrict__ csr, const float* __restrict__ W2l,
    const float* __restrict__ b2, const float* __restrict__ W2r,
    float* __restrict__ out, int N) {
  __shared__ float Wl[DOUT][DW];
  __shared__ float Wr[DOUT][DW];
  __shared__ float hs[4][D];
  __shared__ float ms[4][D];
  for (int i = threadIdx.x; i < DOUT * D; i += 256) {
    int r = i >> 6, c = i & 63;
    Wl[r][c] = W2l[i];
    Wr[r][c] = W2r[i];
  }
  __syncthreads();
  int wave = threadIdx.x >> 6;
  int lane = threadIdx.x & 63;
  int g = lane >> 3;
  int t = lane & 7;
  float bias = (lane < DOUT) ? b2[lane] : 0.0f;
  int wid = blockIdx.x * 4 + wave;
  int nw = gridDim.x * 4;
  for (int node = wid; node < N; node += nw) {
    int rs = row_start[node];
    int re = row_start[node + 1];
    float acc[8] = {0.f, 0.f, 0.f, 0.f, 0.f, 0.f, 0.f, 0.f};
    int e = rs + g;
    for (; e + 8 < re; e += 16) {
      int s0 = csr[e];
      int s1 = csr[e + 8];
      uint4 r0 = *reinterpret_cast<const uint4*>(hbf + (size_t)s0 * D + t * 8);
      uint4 r1 = *reinterpret_cast<const uint4*>(hbf + (size_t)s1 * D + t * 8);
      addrow(acc, r0);
      addrow(acc, r1);
    }
    if (e < re) {
      int s0 = csr[e];
      uint4 r0 = *reinterpret_cast<const uint4*>(hbf + (size_t)s0 * D + t * 8);
      addrow(acc, r0);
    }
#pragma unroll
    for (int j = 0; j < 8; ++j) {
      acc[j] += __shfl_xor(acc[j], 8, 64);
      acc[j] += __shfl_xor(acc[j], 16, 64);
      acc[j] += __shfl_xor(acc[j], 32, 64);
    }
    float inv = 1.0f / fmaxf((float)(re - rs), 1.0f);
    if (g == 0) {
      float4 m0 = make_float4(acc[0] * inv, acc[1] * inv, acc[2] * inv, acc[3] * inv);
      float4 m1 = make_float4(acc[4] * inv, acc[5] * inv, acc[6] * inv, acc[7] * inv);
      *reinterpret_cast<float4*>(&ms[wave][t * 8]) = m0;
      *reinterpret_cast<float4*>(&ms[wave][t * 8 + 4]) = m1;
    }
    hs[wave][lane] = bf2f(hbf[(size_t)node * D + lane]);
    float o = bias;
    if (lane < DOUT) {
#pragma unroll
      for (int k = 0; k < D; k += 4) {
        float4 m = *reinterpret_cast<const float4*>(&ms[wave][k]);
        float4 hv = *reinterpret_cast<const float4*>(&hs[wave][k]);
        float4 wl = *reinterpret_cast<const float4*>(&Wl[lane][k]);
        float4 wr = *reinterpret_cast<const float4*>(&Wr[lane][k]);
        o += m.x * wl.x + m.y * wl.y + m.z * wl.z + m.w * wl.w;
        o += hv.x * wr.x + hv.y * wr.y + hv.z * wr.z + hv.w * wr.w;
      }
    }
    float v = (lane < DOUT) ? o : -INFINITY;
    float mx = v;
    for (int off = 32; off; off >>= 1) mx = fmaxf(mx, __shfl_xor(mx, off, 64));
    float ex = (lane < DOUT) ? expf(o - mx) : 0.0f;
    float sm = ex;
    for (int off = 32; off; off >>= 1) sm += __shfl_xor(sm, off, 64);
    if (lane < DOUT) out[(size_t)node * DOUT + lane] = o - mx - logf(sm);
  }
}

extern "C" void kernel_launch(void* const* d_in, const int* in_sizes, int n_in,
                              void* d_out, int out_size, void* d_ws, size_t ws_size,
                              hipStream_t stream) {
  const float* x   = (const float*)d_in[0];
  const int*   ei  = (const int*)d_in[1];
  const float* W1l = (const float*)d_in[2];
  const float* b1  = (const float*)d_in[3];
  const float* W1r = (const float*)d_in[4];
  const float* W2l = (const float*)d_in[5];
  const float* b2  = (const float*)d_in[6];
  const float* W2r = (const float*)d_in[7];
  float* out = (float*)d_out;

  const int* src = ei;
  const int* dst = ei + N_EDGES;

  char* ws = (char*)d_ws;
  size_t featB = (size_t)N_NODES * D * sizeof(unsigned short);  // 12.8 MB
  unsigned short* xbf = (unsigned short*)ws;
  unsigned short* hbf = (unsigned short*)(ws + featB);
  int*      csr    = (int*)(ws + 2 * featB);                    // 6.4 MB
  unsigned* binned = (unsigned*)(csr + N_EDGES);                // 6.4 MB
  int* row_start   = (int*)(binned + N_EDGES);                  // (N+1) ints
  int* bcnt        = row_start + N_NODES + 1;                   // NBUCK
  int* bstart      = bcnt + NBUCK;                              // NBUCK+1
  int* bcursor     = bstart + NBUCK + 1;                        // NBUCK

  const int NCHUNK = (N_EDGES + 4095) / 4096;   // 391 chunks

  // ---- bf16 feature cache ----
  cvt_kernel<<<(N_NODES * D / 8 + 255) / 256, 256, 0, stream>>>(x, xbf, N_NODES * D / 8);

  // ---- build CSR (two-level bucket sort) ----
  hipMemsetAsync(bcnt, 0, NBUCK * sizeof(int), stream);
  bhist_kernel<<<NCHUNK, 256, 0, stream>>>(dst, bcnt, N_EDGES);
  bscan_kernel<<<1, 256, 0, stream>>>(bcnt, bstart, bcursor, N_EDGES);
  bscatter_kernel<<<NCHUNK, 256, 0, stream>>>(src, dst, bcursor, binned, N_EDGES);
  bfine_kernel<<<NBUCK, 256, 0, stream>>>(binned, bstart, row_start, csr, N_NODES, N_EDGES);

  // ---- fused layers ----
  sage1_kernel<<<2048, 256, 0, stream>>>(x, xbf, row_start, csr, W1l, b1, W1r, hbf, N_NODES);
  sage2_kernel<<<2048, 256, 0, stream>>>(hbf, row_start, csr, W2l, b2, W2r, out, N_NODES);
}

// Round 7
// 284.310 us; speedup vs baseline: 10.4899x; 1.0286x over previous
//
#include <hip/hip_runtime.h>
#include <math.h>

#define N_NODES 100000
#define N_EDGES 1600000
#define D 64
#define DW 68   // padded f32 weight row (16B-aligned)
#define DOUT 40
#define NBUCK ((N_NODES + 255) / 256)   // 391 coarse buckets of 256 dst-nodes

__device__ inline float bf2f(unsigned u) {
  union { unsigned i; float f; } v;
  v.i = u << 16;
  return v.f;
}
__device__ inline unsigned f2bf(float f) {
  union { float f; unsigned i; } v;
  v.f = f;
  unsigned r = v.i + 0x7fffu + ((v.i >> 16) & 1u);   // RNE
  return r >> 16;
}
__device__ inline void addrow(float* acc, uint4 r) {
  acc[0] += bf2f(r.x & 0xffffu); acc[1] += bf2f(r.x >> 16);
  acc[2] += bf2f(r.y & 0xffffu); acc[3] += bf2f(r.y >> 16);
  acc[4] += bf2f(r.z & 0xffffu); acc[5] += bf2f(r.z >> 16);
  acc[6] += bf2f(r.w & 0xffffu); acc[7] += bf2f(r.w >> 16);
}

// ---------------------------------------------------------------------------
// f32 -> bf16 convert (8 floats / thread)
// ---------------------------------------------------------------------------
__global__ __launch_bounds__(256) void cvt_kernel(const float* __restrict__ in,
                                                  unsigned short* __restrict__ ob,
                                                  int n8) {
  int i = blockIdx.x * 256 + threadIdx.x;
  if (i >= n8) return;
  const float4* p = reinterpret_cast<const float4*>(in) + (size_t)i * 2;
  float4 a = p[0], b = p[1];
  uint4 o;
  o.x = f2bf(a.x) | (f2bf(a.y) << 16);
  o.y = f2bf(a.z) | (f2bf(a.w) << 16);
  o.z = f2bf(b.x) | (f2bf(b.y) << 16);
  o.w = f2bf(b.z) | (f2bf(b.w) << 16);
  reinterpret_cast<uint4*>(ob)[i] = o;
}

// ---------------------------------------------------------------------------
// CSR build: two-level bucket sort (write-locality-aware)
// bucket(d) = d >> 8 ; entry = (dstLocal << 24) | src  (src < 2^24)
// ---------------------------------------------------------------------------
__global__ __launch_bounds__(256) void bhist_kernel(const int* __restrict__ dst,
                                                    int* __restrict__ bcnt, int E) {
  __shared__ int c[512];
  int t = threadIdx.x;
  c[t] = 0; c[t + 256] = 0;
  __syncthreads();
  int cbase = blockIdx.x * 4096;
  int cc = min(4096, E - cbase);
  for (int i = t; i < cc; i += 256) atomicAdd(&c[dst[cbase + i] >> 8], 1);
  __syncthreads();
  for (int b = t; b < NBUCK; b += 256)
    if (c[b]) atomicAdd(&bcnt[b], c[b]);
}

__global__ __launch_bounds__(256) void bscan_kernel(const int* __restrict__ bcnt,
                                                    int* __restrict__ bstart,
                                                    int* __restrict__ bcursor, int E) {
  __shared__ int s[512];
  int t = threadIdx.x;
  int o0 = (t < NBUCK) ? bcnt[t] : 0;
  int o1 = (t + 256 < NBUCK) ? bcnt[t + 256] : 0;
  s[t] = o0; s[t + 256] = o1;
  __syncthreads();
  for (int off = 1; off < 512; off <<= 1) {
    int v0 = (t >= off) ? s[t - off] : 0;
    int v1 = s[t + 256 - off];
    __syncthreads();
    s[t] += v0; s[t + 256] += v1;
    __syncthreads();
  }
  if (t < NBUCK) { bstart[t] = s[t] - o0; bcursor[t] = s[t] - o0; }
  if (t + 256 < NBUCK) { bstart[t + 256] = s[t + 256] - o1; bcursor[t + 256] = s[t + 256] - o1; }
  if (t == 0) bstart[NBUCK] = E;
}

__global__ __launch_bounds__(256) void bscatter_kernel(const int* __restrict__ src,
                                                       const int* __restrict__ dst,
                                                       int* __restrict__ bcursor,
                                                       unsigned* __restrict__ binned,
                                                       int E) {
  __shared__ unsigned ent[4096];
  __shared__ unsigned short sbk[4096];
  __shared__ int cnt[512], scn[512], pos[512], base[512];
  int t = threadIdx.x;
  int cbase = blockIdx.x * 4096;
  int cc = min(4096, E - cbase);
  cnt[t] = 0; cnt[t + 256] = 0;
  __syncthreads();
  unsigned my_e[16];
  int my_b[16];
  int nmine = 0;
#pragma unroll
  for (int i = 0; i < 16; ++i) {
    int li = t + i * 256;
    if (li < cc) {
      int s = src[cbase + li];
      int d = dst[cbase + li];
      int b = d >> 8;
      my_e[nmine] = ((unsigned)(d & 255) << 24) | (unsigned)s;
      my_b[nmine] = b;
      nmine++;
      atomicAdd(&cnt[b], 1);
    }
  }
  __syncthreads();
  scn[t] = cnt[t]; scn[t + 256] = cnt[t + 256];
  __syncthreads();
  for (int off = 1; off < 512; off <<= 1) {
    int v0 = (t >= off) ? scn[t - off] : 0;
    int v1 = scn[t + 256 - off];
    __syncthreads();
    scn[t] += v0; scn[t + 256] += v1;
    __syncthreads();
  }
  pos[t] = scn[t] - cnt[t];
  pos[t + 256] = scn[t + 256] - cnt[t + 256];
  __syncthreads();
  for (int i = 0; i < nmine; ++i) {
    int slot = atomicAdd(&pos[my_b[i]], 1);
    ent[slot] = my_e[i];
    sbk[slot] = (unsigned short)my_b[i];
  }
  __syncthreads();
  for (int b = t; b < NBUCK; b += 256)
    if (cnt[b] > 0) base[b] = atomicAdd(&bcursor[b], cnt[b]);
  __syncthreads();
  for (int i = t; i < cc; i += 256) {
    int b = sbk[i];
    int excl = scn[b] - cnt[b];
    binned[base[b] + (i - excl)] = ent[i];
  }
}

__global__ __launch_bounds__(256) void bfine_kernel(const unsigned* __restrict__ binned,
                                                    const int* __restrict__ bstart,
                                                    int* __restrict__ row_start,
                                                    int* __restrict__ csr, int N, int E) {
  __shared__ int c[256], p[256], pos[256];
  int b = blockIdx.x;
  int t = threadIdx.x;
  int s0 = bstart[b], s1 = bstart[b + 1];
  c[t] = 0;
  __syncthreads();
  for (int i = s0 + t; i < s1; i += 256)
    atomicAdd(&c[binned[i] >> 24], 1);
  __syncthreads();
  p[t] = c[t];
  __syncthreads();
  for (int off = 1; off < 256; off <<= 1) {
    int v = (t >= off) ? p[t - off] : 0;
    __syncthreads();
    p[t] += v;
    __syncthreads();
  }
  int excl = p[t] - c[t];
  int node = b * 256 + t;
  if (node < N) row_start[node] = s0 + excl;
  if (b == 0 && t == 0) row_start[N] = E;
  pos[t] = excl;
  __syncthreads();
  for (int i = s0 + t; i < s1; i += 256) {
    unsigned u = binned[i];
    int slot = atomicAdd(&pos[u >> 24], 1);
    csr[s0 + slot] = (int)(u & 0xFFFFFFu);
  }
}

// ---------------------------------------------------------------------------
// Aggregation only: one wave per node, zero LDS -> high occupancy for the
// random gather. Wave = 8 groups x 8 lanes; group g owns an edge, lane t
// loads uint4 = 8 bf16 feats. Butterfly fold, then lane (g,t) writes
// feature t*8+g of the bf16 mean row (128B coalesced per wave).
// ---------------------------------------------------------------------------
__global__ __launch_bounds__(256) void agg_kernel(
    const unsigned short* __restrict__ feat, const int* __restrict__ row_start,
    const int* __restrict__ csr, unsigned short* __restrict__ msbf, int N) {
  int wid = (blockIdx.x * 256 + threadIdx.x) >> 6;
  if (wid >= N) return;
  int lane = threadIdx.x & 63;
  int g = lane >> 3;
  int t = lane & 7;
  int rs = row_start[wid], re = row_start[wid + 1];
  float acc[8] = {0.f, 0.f, 0.f, 0.f, 0.f, 0.f, 0.f, 0.f};
  int e = rs + g;
  for (; e + 8 < re; e += 16) {
    int s0 = csr[e];
    int s1 = csr[e + 8];
    uint4 r0 = *reinterpret_cast<const uint4*>(feat + (size_t)s0 * D + t * 8);
    uint4 r1 = *reinterpret_cast<const uint4*>(feat + (size_t)s1 * D + t * 8);
    addrow(acc, r0);
    addrow(acc, r1);
  }
  if (e < re) {
    int s0 = csr[e];
    uint4 r0 = *reinterpret_cast<const uint4*>(feat + (size_t)s0 * D + t * 8);
    addrow(acc, r0);
  }
#pragma unroll
  for (int j = 0; j < 8; ++j) {
    acc[j] += __shfl_xor(acc[j], 8, 64);
    acc[j] += __shfl_xor(acc[j], 16, 64);
    acc[j] += __shfl_xor(acc[j], 32, 64);
  }
  float inv = 1.0f / fmaxf((float)(re - rs), 1.0f);
  float mv = acc[0];
#pragma unroll
  for (int j = 1; j < 8; ++j)
    if (g == j) mv = acc[j];      // static-index cndmask chain (no scratch)
  msbf[(size_t)wid * D + t * 8 + g] = (unsigned short)f2bf(mv * inv);
}

// ---------------------------------------------------------------------------
// Linear 1: h = relu(mean @ W1l^T + b1 + x @ W1r^T), mean bf16, out bf16
// ---------------------------------------------------------------------------
__global__ __launch_bounds__(256) void lin1_kernel(
    const float* __restrict__ x, const unsigned short* __restrict__ msbf,
    const float* __restrict__ W1l, const float* __restrict__ b1,
    const float* __restrict__ W1r, unsigned short* __restrict__ hbf, int N) {
  __shared__ float Wl[D][DW];
  __shared__ float Wr[D][DW];
  __shared__ float msL[4][D];
  __shared__ float xsL[4][D];
  for (int i = threadIdx.x; i < D * D; i += 256) {
    int r = i >> 6, c = i & 63;
    Wl[r][c] = W1l[i];
    Wr[r][c] = W1r[i];
  }
  __syncthreads();
  int wave = threadIdx.x >> 6;
  int lane = threadIdx.x & 63;
  float bias = b1[lane];
  int wid = blockIdx.x * 4 + wave;
  int nw = gridDim.x * 4;
  for (int node = wid; node < N; node += nw) {
    msL[wave][lane] = bf2f(msbf[(size_t)node * D + lane]);
    xsL[wave][lane] = x[(size_t)node * D + lane];
    float o = bias;
#pragma unroll
    for (int k = 0; k < D; k += 4) {
      float4 m = *reinterpret_cast<const float4*>(&msL[wave][k]);
      float4 xv = *reinterpret_cast<const float4*>(&xsL[wave][k]);
      float4 wl = *reinterpret_cast<const float4*>(&Wl[lane][k]);
      float4 wr = *reinterpret_cast<const float4*>(&Wr[lane][k]);
      o += m.x * wl.x + m.y * wl.y + m.z * wl.z + m.w * wl.w;
      o += xv.x * wr.x + xv.y * wr.y + xv.z * wr.z + xv.w * wr.w;
    }
    hbf[(size_t)node * D + lane] = (unsigned short)f2bf(fmaxf(o, 0.0f));
  }
}

// ---------------------------------------------------------------------------
// Linear 2 + log_softmax: o = mean2 @ W2l^T + b2 + h @ W2r^T
// ---------------------------------------------------------------------------
__global__ __launch_bounds__(256) void lin2_kernel(
    const unsigned short* __restrict__ hbf, const unsigned short* __restrict__ msbf,
    const float* __restrict__ W2l, const float* __restrict__ b2,
    const float* __restrict__ W2r, float* __restrict__ out, int N) {
  __shared__ float Wl[DOUT][DW];
  __shared__ float Wr[DOUT][DW];
  __shared__ float hsL[4][D];
  __shared__ float msL[4][D];
  for (int i = threadIdx.x; i < DOUT * D; i += 256) {
    int r = i >> 6, c = i & 63;
    Wl[r][c] = W2l[i];
    Wr[r][c] = W2r[i];
  }
  __syncthreads();
  int wave = threadIdx.x >> 6;
  int lane = threadIdx.x & 63;
  float bias = (lane < DOUT) ? b2[lane] : 0.0f;
  int wid = blockIdx.x * 4 + wave;
  int nw = gridDim.x * 4;
  for (int node = wid; node < N; node += nw) {
    msL[wave][lane] = bf2f(msbf[(size_t)node * D + lane]);
    hsL[wave][lane] = bf2f(hbf[(size_t)node * D + lane]);
    float o = bias;
    if (lane < DOUT) {
#pragma unroll
      for (int k = 0; k < D; k += 4) {
        float4 m = *reinterpret_cast<const float4*>(&msL[wave][k]);
        float4 hv = *reinterpret_cast<const float4*>(&hsL[wave][k]);
        float4 wl = *reinterpret_cast<const float4*>(&Wl[lane][k]);
        float4 wr = *reinterpret_cast<const float4*>(&Wr[lane][k]);
        o += m.x * wl.x + m.y * wl.y + m.z * wl.z + m.w * wl.w;
        o += hv.x * wr.x + hv.y * wr.y + hv.z * wr.z + hv.w * wr.w;
      }
    }
    float v = (lane < DOUT) ? o : -INFINITY;
    float mx = v;
    for (int off = 32; off; off >>= 1) mx = fmaxf(mx, __shfl_xor(mx, off, 64));
    float ex = (lane < DOUT) ? expf(o - mx) : 0.0f;
    float sm = ex;
    for (int off = 32; off; off >>= 1) sm += __shfl_xor(sm, off, 64);
    if (lane < DOUT) out[(size_t)node * DOUT + lane] = o - mx - logf(sm);
  }
}

extern "C" void kernel_launch(void* const* d_in, const int* in_sizes, int n_in,
                              void* d_out, int out_size, void* d_ws, size_t ws_size,
                              hipStream_t stream) {
  const float* x   = (const float*)d_in[0];
  const int*   ei  = (const int*)d_in[1];
  const float* W1l = (const float*)d_in[2];
  const float* b1  = (const float*)d_in[3];
  const float* W1r = (const float*)d_in[4];
  const float* W2l = (const float*)d_in[5];
  const float* b2  = (const float*)d_in[6];
  const float* W2r = (const float*)d_in[7];
  float* out = (float*)d_out;

  const int* src = ei;
  const int* dst = ei + N_EDGES;

  // Workspace layout (peak ~45.2 MB):
  //   xbf(12.8M) | hbf(12.8M) | csr(6.4M) | row_start | bcnt|bstart|bcursor |
  //   scratch(12.8M): binned(6.4M, dead after bfine) then reused as ms1.
  //   ms2 aliases xbf (dead after agg1).
  char* ws = (char*)d_ws;
  size_t featB = (size_t)N_NODES * D * sizeof(unsigned short);  // 12.8 MB
  unsigned short* xbf = (unsigned short*)ws;
  unsigned short* hbf = (unsigned short*)(ws + featB);
  int* csr       = (int*)(ws + 2 * featB);                      // 6.4 MB
  int* row_start = csr + N_EDGES;                               // (N+1) ints
  int* bcnt      = row_start + N_NODES + 1;
  int* bstart    = bcnt + NBUCK;
  int* bcursor   = bstart + NBUCK + 1;
  char* scratch  = (char*)(bcursor + NBUCK);
  scratch = (char*)(((uintptr_t)scratch + 15) & ~(uintptr_t)15);
  unsigned* binned     = (unsigned*)scratch;                    // 6.4 MB
  unsigned short* ms1  = (unsigned short*)scratch;              // 12.8 MB (after bfine)
  unsigned short* ms2  = xbf;                                   // after agg1

  const int NCHUNK = (N_EDGES + 4095) / 4096;   // 391 chunks
  const int AGG_BLOCKS = (N_NODES + 3) / 4;     // one wave per node

  // ---- bf16 feature cache ----
  cvt_kernel<<<(N_NODES * D / 8 + 255) / 256, 256, 0, stream>>>(x, xbf, N_NODES * D / 8);

  // ---- build CSR (two-level bucket sort) ----
  hipMemsetAsync(bcnt, 0, NBUCK * sizeof(int), stream);
  bhist_kernel<<<NCHUNK, 256, 0, stream>>>(dst, bcnt, N_EDGES);
  bscan_kernel<<<1, 256, 0, stream>>>(bcnt, bstart, bcursor, N_EDGES);
  bscatter_kernel<<<NCHUNK, 256, 0, stream>>>(src, dst, bcursor, binned, N_EDGES);
  bfine_kernel<<<NBUCK, 256, 0, stream>>>(binned, bstart, row_start, csr, N_NODES, N_EDGES);

  // ---- layer 1: gather (high-occupancy) then linear ----
  agg_kernel<<<AGG_BLOCKS, 256, 0, stream>>>(xbf, row_start, csr, ms1, N_NODES);
  lin1_kernel<<<2048, 256, 0, stream>>>(x, ms1, W1l, b1, W1r, hbf, N_NODES);

  // ---- layer 2: gather then linear+softmax ----
  agg_kernel<<<AGG_BLOCKS, 256, 0, stream>>>(hbf, row_start, csr, ms2, N_NODES);
  lin2_kernel<<<2048, 256, 0, stream>>>(hbf, ms2, W2l, b2, W2r, out, N_NODES);
}

// Round 8
// 184.856 us; speedup vs baseline: 16.1336x; 1.5380x over previous
//
#include <hip/hip_runtime.h>
#include <math.h>

#define N_NODES 100000
#define N_EDGES 1600000
#define D 64
#define DOUT 40
#define NBUCK ((N_NODES + 255) / 256)   // 391 coarse buckets of 256 dst-nodes

typedef __attribute__((ext_vector_type(8))) short bf16x8v;   // 8 bf16 (4 VGPRs)
typedef __attribute__((ext_vector_type(4))) float f32x4v;    // MFMA accumulator

__device__ inline float bf2f(unsigned u) {
  union { unsigned i; float f; } v;
  v.i = u << 16;
  return v.f;
}
__device__ inline unsigned f2bf(float f) {
  union { float f; unsigned i; } v;
  v.f = f;
  unsigned r = v.i + 0x7fffu + ((v.i >> 16) & 1u);   // RNE
  return r >> 16;
}
__device__ inline void addrow(float* acc, uint4 r) {
  acc[0] += bf2f(r.x & 0xffffu); acc[1] += bf2f(r.x >> 16);
  acc[2] += bf2f(r.y & 0xffffu); acc[3] += bf2f(r.y >> 16);
  acc[4] += bf2f(r.z & 0xffffu); acc[5] += bf2f(r.z >> 16);
  acc[6] += bf2f(r.w & 0xffffu); acc[7] += bf2f(r.w >> 16);
}

// ---------------------------------------------------------------------------
// f32 -> bf16 convert (8 floats / thread)
// ---------------------------------------------------------------------------
__global__ __launch_bounds__(256) void cvt_kernel(const float* __restrict__ in,
                                                  unsigned short* __restrict__ ob,
                                                  int n8) {
  int i = blockIdx.x * 256 + threadIdx.x;
  if (i >= n8) return;
  const float4* p = reinterpret_cast<const float4*>(in) + (size_t)i * 2;
  float4 a = p[0], b = p[1];
  uint4 o;
  o.x = f2bf(a.x) | (f2bf(a.y) << 16);
  o.y = f2bf(a.z) | (f2bf(a.w) << 16);
  o.z = f2bf(b.x) | (f2bf(b.y) << 16);
  o.w = f2bf(b.z) | (f2bf(b.w) << 16);
  reinterpret_cast<uint4*>(ob)[i] = o;
}

// ---------------------------------------------------------------------------
// Weight prep: Wcat1[64][128] = [W1l | W1r] bf16; Wcat2[48][128] = [W2l | W2r]
// (rows 40..47 zero); b2p[48] padded bias.
// ---------------------------------------------------------------------------
__global__ __launch_bounds__(256) void wcvt_kernel(
    const float* __restrict__ W1l, const float* __restrict__ W1r,
    const float* __restrict__ W2l, const float* __restrict__ W2r,
    const float* __restrict__ b2, unsigned short* __restrict__ Wcat1,
    unsigned short* __restrict__ Wcat2, float* __restrict__ b2p) {
  int i = blockIdx.x * 256 + threadIdx.x;
  if (i < 64 * 128) {
    int o = i >> 7, k = i & 127;
    float v = (k < 64) ? W1l[o * 64 + k] : W1r[o * 64 + (k - 64)];
    Wcat1[i] = (unsigned short)f2bf(v);
  } else if (i < 64 * 128 + 48 * 128) {
    int j = i - 64 * 128;
    int o = j >> 7, k = j & 127;
    float v = (o < DOUT) ? ((k < 64) ? W2l[o * 64 + k] : W2r[o * 64 + (k - 64)]) : 0.0f;
    Wcat2[j] = (unsigned short)f2bf(v);
  } else if (i < 64 * 128 + 48 * 128 + 48) {
    int j = i - 64 * 128 - 48 * 128;
    b2p[j] = (j < DOUT) ? b2[j] : 0.0f;
  }
}

// ---------------------------------------------------------------------------
// CSR build: two-level bucket sort (write-locality-aware)
// ---------------------------------------------------------------------------
__global__ __launch_bounds__(256) void bhist_kernel(const int* __restrict__ dst,
                                                    int* __restrict__ bcnt, int E) {
  __shared__ int c[512];
  int t = threadIdx.x;
  c[t] = 0; c[t + 256] = 0;
  __syncthreads();
  int cbase = blockIdx.x * 4096;
  int cc = min(4096, E - cbase);
  for (int i = t; i < cc; i += 256) atomicAdd(&c[dst[cbase + i] >> 8], 1);
  __syncthreads();
  for (int b = t; b < NBUCK; b += 256)
    if (c[b]) atomicAdd(&bcnt[b], c[b]);
}

__global__ __launch_bounds__(256) void bscan_kernel(const int* __restrict__ bcnt,
                                                    int* __restrict__ bstart,
                                                    int* __restrict__ bcursor, int E) {
  __shared__ int s[512];
  int t = threadIdx.x;
  int o0 = (t < NBUCK) ? bcnt[t] : 0;
  int o1 = (t + 256 < NBUCK) ? bcnt[t + 256] : 0;
  s[t] = o0; s[t + 256] = o1;
  __syncthreads();
  for (int off = 1; off < 512; off <<= 1) {
    int v0 = (t >= off) ? s[t - off] : 0;
    int v1 = s[t + 256 - off];
    __syncthreads();
    s[t] += v0; s[t + 256] += v1;
    __syncthreads();
  }
  if (t < NBUCK) { bstart[t] = s[t] - o0; bcursor[t] = s[t] - o0; }
  if (t + 256 < NBUCK) { bstart[t + 256] = s[t + 256] - o1; bcursor[t + 256] = s[t + 256] - o1; }
  if (t == 0) bstart[NBUCK] = E;
}

__global__ __launch_bounds__(256) void bscatter_kernel(const int* __restrict__ src,
                                                       const int* __restrict__ dst,
                                                       int* __restrict__ bcursor,
                                                       unsigned* __restrict__ binned,
                                                       int E) {
  __shared__ unsigned ent[4096];
  __shared__ unsigned short sbk[4096];
  __shared__ int cnt[512], scn[512], pos[512], base[512];
  int t = threadIdx.x;
  int cbase = blockIdx.x * 4096;
  int cc = min(4096, E - cbase);
  cnt[t] = 0; cnt[t + 256] = 0;
  __syncthreads();
  unsigned my_e[16];
  int my_b[16];
  int nmine = 0;
#pragma unroll
  for (int i = 0; i < 16; ++i) {
    int li = t + i * 256;
    if (li < cc) {
      int s = src[cbase + li];
      int d = dst[cbase + li];
      int b = d >> 8;
      my_e[nmine] = ((unsigned)(d & 255) << 24) | (unsigned)s;
      my_b[nmine] = b;
      nmine++;
      atomicAdd(&cnt[b], 1);
    }
  }
  __syncthreads();
  scn[t] = cnt[t]; scn[t + 256] = cnt[t + 256];
  __syncthreads();
  for (int off = 1; off < 512; off <<= 1) {
    int v0 = (t >= off) ? scn[t - off] : 0;
    int v1 = scn[t + 256 - off];
    __syncthreads();
    scn[t] += v0; scn[t + 256] += v1;
    __syncthreads();
  }
  pos[t] = scn[t] - cnt[t];
  pos[t + 256] = scn[t + 256] - cnt[t + 256];
  __syncthreads();
  for (int i = 0; i < nmine; ++i) {
    int slot = atomicAdd(&pos[my_b[i]], 1);
    ent[slot] = my_e[i];
    sbk[slot] = (unsigned short)my_b[i];
  }
  __syncthreads();
  for (int b = t; b < NBUCK; b += 256)
    if (cnt[b] > 0) base[b] = atomicAdd(&bcursor[b], cnt[b]);
  __syncthreads();
  for (int i = t; i < cc; i += 256) {
    int b = sbk[i];
    int excl = scn[b] - cnt[b];
    binned[base[b] + (i - excl)] = ent[i];
  }
}

__global__ __launch_bounds__(256) void bfine_kernel(const unsigned* __restrict__ binned,
                                                    const int* __restrict__ bstart,
                                                    int* __restrict__ row_start,
                                                    int* __restrict__ csr, int N, int E) {
  __shared__ int c[256], p[256], pos[256];
  int b = blockIdx.x;
  int t = threadIdx.x;
  int s0 = bstart[b], s1 = bstart[b + 1];
  c[t] = 0;
  __syncthreads();
  for (int i = s0 + t; i < s1; i += 256)
    atomicAdd(&c[binned[i] >> 24], 1);
  __syncthreads();
  p[t] = c[t];
  __syncthreads();
  for (int off = 1; off < 256; off <<= 1) {
    int v = (t >= off) ? p[t - off] : 0;
    __syncthreads();
    p[t] += v;
    __syncthreads();
  }
  int excl = p[t] - c[t];
  int node = b * 256 + t;
  if (node < N) row_start[node] = s0 + excl;
  if (b == 0 && t == 0) row_start[N] = E;
  pos[t] = excl;
  __syncthreads();
  for (int i = s0 + t; i < s1; i += 256) {
    unsigned u = binned[i];
    int slot = atomicAdd(&pos[u >> 24], 1);
    csr[s0 + slot] = (int)(u & 0xFFFFFFu);
  }
}

// ---------------------------------------------------------------------------
// Aggregation: one wave per node, zero LDS. 8 groups x 8 lanes; butterfly
// fold; lane (g,t) writes feature t*8+g of the bf16 mean row.
// ---------------------------------------------------------------------------
__global__ __launch_bounds__(256) void agg_kernel(
    const unsigned short* __restrict__ feat, const int* __restrict__ row_start,
    const int* __restrict__ csr, unsigned short* __restrict__ msbf, int N) {
  int wid = (blockIdx.x * 256 + threadIdx.x) >> 6;
  if (wid >= N) return;
  int lane = threadIdx.x & 63;
  int g = lane >> 3;
  int t = lane & 7;
  int rs = row_start[wid], re = row_start[wid + 1];
  float acc[8] = {0.f, 0.f, 0.f, 0.f, 0.f, 0.f, 0.f, 0.f};
  int e = rs + g;
  for (; e + 8 < re; e += 16) {
    int s0 = csr[e];
    int s1 = csr[e + 8];
    uint4 r0 = *reinterpret_cast<const uint4*>(feat + (size_t)s0 * D + t * 8);
    uint4 r1 = *reinterpret_cast<const uint4*>(feat + (size_t)s1 * D + t * 8);
    addrow(acc, r0);
    addrow(acc, r1);
  }
  if (e < re) {
    int s0 = csr[e];
    uint4 r0 = *reinterpret_cast<const uint4*>(feat + (size_t)s0 * D + t * 8);
    addrow(acc, r0);
  }
#pragma unroll
  for (int j = 0; j < 8; ++j) {
    acc[j] += __shfl_xor(acc[j], 8, 64);
    acc[j] += __shfl_xor(acc[j], 16, 64);
    acc[j] += __shfl_xor(acc[j], 32, 64);
  }
  float inv = 1.0f / fmaxf((float)(re - rs), 1.0f);
  float mv = acc[0];
#pragma unroll
  for (int j = 1; j < 8; ++j)
    if (g == j) mv = acc[j];      // static-index cndmask chain (no scratch)
  msbf[(size_t)wid * D + t * 8 + g] = (unsigned short)f2bf(mv * inv);
}

// ---------------------------------------------------------------------------
// MFMA linear 1: h = relu([ms|x] @ Wcat1^T + b1), one wave per 16-node tile.
// A-frag: row = lane&15 (node), k = kk*32 + (lane>>4)*8 + i (16B loads).
// B-frag: col = lane&15 (out feat), same k from Wcat1[o][128].
// C/D: col = lane&15, row = (lane>>4)*4 + reg  [m89-verified].
// ---------------------------------------------------------------------------
__global__ __launch_bounds__(256) void lin1_kernel(
    const unsigned short* __restrict__ xbf, const unsigned short* __restrict__ msbf,
    const unsigned short* __restrict__ Wcat, const float* __restrict__ b1,
    unsigned short* __restrict__ hbf, int N) {
  int wid = (blockIdx.x * 256 + threadIdx.x) >> 6;   // tile id
  int ntiles = N >> 4;                               // 6250 (N % 16 == 0)
  if (wid >= ntiles) return;
  int lane = threadIdx.x & 63;
  int col = lane & 15;
  int k0 = (lane >> 4) * 8;
  int base = wid * 16;
  const unsigned short* am = msbf + (size_t)(base + col) * D;
  const unsigned short* ax = xbf + (size_t)(base + col) * D;
  bf16x8v a0 = *(const bf16x8v*)(am + k0);
  bf16x8v a1 = *(const bf16x8v*)(am + 32 + k0);
  bf16x8v a2 = *(const bf16x8v*)(ax + k0);
  bf16x8v a3 = *(const bf16x8v*)(ax + 32 + k0);
  f32x4v acc0 = {0.f, 0.f, 0.f, 0.f}, acc1 = acc0, acc2 = acc0, acc3 = acc0;
#define LIN1_CT(CT, ACC)                                                      \
  {                                                                           \
    const unsigned short* w = Wcat + ((CT)*16 + col) * 128 + k0;              \
    bf16x8v b0 = *(const bf16x8v*)(w);                                        \
    bf16x8v b1v = *(const bf16x8v*)(w + 32);                                  \
    bf16x8v b2v = *(const bf16x8v*)(w + 64);                                  \
    bf16x8v b3v = *(const bf16x8v*)(w + 96);                                  \
    ACC = __builtin_amdgcn_mfma_f32_16x16x32_bf16(a0, b0, ACC, 0, 0, 0);      \
    ACC = __builtin_amdgcn_mfma_f32_16x16x32_bf16(a1, b1v, ACC, 0, 0, 0);     \
    ACC = __builtin_amdgcn_mfma_f32_16x16x32_bf16(a2, b2v, ACC, 0, 0, 0);     \
    ACC = __builtin_amdgcn_mfma_f32_16x16x32_bf16(a3, b3v, ACC, 0, 0, 0);     \
  }
  LIN1_CT(0, acc0) LIN1_CT(1, acc1) LIN1_CT(2, acc2) LIN1_CT(3, acc3)
#undef LIN1_CT
  int rbase = (lane >> 4) * 4;
  float bias0 = b1[col], bias1 = b1[16 + col], bias2 = b1[32 + col], bias3 = b1[48 + col];
#pragma unroll
  for (int r = 0; r < 4; ++r) {
    size_t rowoff = (size_t)(base + rbase + r) * D;
    hbf[rowoff + col]      = (unsigned short)f2bf(fmaxf(acc0[r] + bias0, 0.f));
    hbf[rowoff + 16 + col] = (unsigned short)f2bf(fmaxf(acc1[r] + bias1, 0.f));
    hbf[rowoff + 32 + col] = (unsigned short)f2bf(fmaxf(acc2[r] + bias2, 0.f));
    hbf[rowoff + 48 + col] = (unsigned short)f2bf(fmaxf(acc3[r] + bias3, 0.f));
  }
}

// ---------------------------------------------------------------------------
// MFMA linear 2 + log_softmax: o = [ms2|h] @ Wcat2^T + b2p (48 cols, 40 valid)
// Softmax per node-row via 16-lane shfl_xor reduction (rows live in 16-lane
// groups under the C/D mapping).
// ---------------------------------------------------------------------------
__global__ __launch_bounds__(256) void lin2_kernel(
    const unsigned short* __restrict__ hbf, const unsigned short* __restrict__ msbf,
    const unsigned short* __restrict__ Wcat, const float* __restrict__ b2p,
    float* __restrict__ out, int N) {
  int wid = (blockIdx.x * 256 + threadIdx.x) >> 6;
  int ntiles = N >> 4;
  if (wid >= ntiles) return;
  int lane = threadIdx.x & 63;
  int col = lane & 15;
  int k0 = (lane >> 4) * 8;
  int base = wid * 16;
  const unsigned short* am = msbf + (size_t)(base + col) * D;
  const unsigned short* ah = hbf + (size_t)(base + col) * D;
  bf16x8v a0 = *(const bf16x8v*)(am + k0);
  bf16x8v a1 = *(const bf16x8v*)(am + 32 + k0);
  bf16x8v a2 = *(const bf16x8v*)(ah + k0);
  bf16x8v a3 = *(const bf16x8v*)(ah + 32 + k0);
  f32x4v acc0 = {0.f, 0.f, 0.f, 0.f}, acc1 = acc0, acc2 = acc0;
#define LIN2_CT(CT, ACC)                                                      \
  {                                                                           \
    const unsigned short* w = Wcat + ((CT)*16 + col) * 128 + k0;              \
    bf16x8v b0 = *(const bf16x8v*)(w);                                        \
    bf16x8v b1v = *(const bf16x8v*)(w + 32);                                  \
    bf16x8v b2v = *(const bf16x8v*)(w + 64);                                  \
    bf16x8v b3v = *(const bf16x8v*)(w + 96);                                  \
    ACC = __builtin_amdgcn_mfma_f32_16x16x32_bf16(a0, b0, ACC, 0, 0, 0);      \
    ACC = __builtin_amdgcn_mfma_f32_16x16x32_bf16(a1, b1v, ACC, 0, 0, 0);     \
    ACC = __builtin_amdgcn_mfma_f32_16x16x32_bf16(a2, b2v, ACC, 0, 0, 0);     \
    ACC = __builtin_amdgcn_mfma_f32_16x16x32_bf16(a3, b3v, ACC, 0, 0, 0);     \
  }
  LIN2_CT(0, acc0) LIN2_CT(1, acc1) LIN2_CT(2, acc2)
#undef LIN2_CT
  int rbase = (lane >> 4) * 4;
  float bias0 = b2p[col], bias1 = b2p[16 + col], bias2 = b2p[32 + col];
  bool v2ok = (col < 8);   // cols 32..39 valid only
#pragma unroll
  for (int r = 0; r < 4; ++r) {
    float v0 = acc0[r] + bias0;
    float v1 = acc1[r] + bias1;
    float v2 = v2ok ? (acc2[r] + bias2) : -INFINITY;
    float mx = fmaxf(fmaxf(v0, v1), v2);
    mx = fmaxf(mx, __shfl_xor(mx, 1, 64));
    mx = fmaxf(mx, __shfl_xor(mx, 2, 64));
    mx = fmaxf(mx, __shfl_xor(mx, 4, 64));
    mx = fmaxf(mx, __shfl_xor(mx, 8, 64));
    float sm = expf(v0 - mx) + expf(v1 - mx) + (v2ok ? expf(v2 - mx) : 0.f);
    sm += __shfl_xor(sm, 1, 64);
    sm += __shfl_xor(sm, 2, 64);
    sm += __shfl_xor(sm, 4, 64);
    sm += __shfl_xor(sm, 8, 64);
    float ls = mx + logf(sm);
    size_t rowoff = (size_t)(base + rbase + r) * DOUT;
    out[rowoff + col] = v0 - ls;
    out[rowoff + 16 + col] = v1 - ls;
    if (v2ok) out[rowoff + 32 + col] = v2 - ls;
  }
}

extern "C" void kernel_launch(void* const* d_in, const int* in_sizes, int n_in,
                              void* d_out, int out_size, void* d_ws, size_t ws_size,
                              hipStream_t stream) {
  const float* x   = (const float*)d_in[0];
  const int*   ei  = (const int*)d_in[1];
  const float* W1l = (const float*)d_in[2];
  const float* b1  = (const float*)d_in[3];
  const float* W1r = (const float*)d_in[4];
  const float* W2l = (const float*)d_in[5];
  const float* b2  = (const float*)d_in[6];
  const float* W2r = (const float*)d_in[7];
  float* out = (float*)d_out;

  const int* src = ei;
  const int* dst = ei + N_EDGES;

  // Workspace (~45.3 MB): xbf | hbf | csr | row_start | bcnt/bstart/bcursor |
  // scratch(12.8M: binned then ms1) | Wcat1 | Wcat2 | b2p.  ms2 aliases xbf.
  char* ws = (char*)d_ws;
  size_t featB = (size_t)N_NODES * D * sizeof(unsigned short);  // 12.8 MB
  unsigned short* xbf = (unsigned short*)ws;
  unsigned short* hbf = (unsigned short*)(ws + featB);
  int* csr       = (int*)(ws + 2 * featB);                      // 6.4 MB
  int* row_start = csr + N_EDGES;                               // (N+1) ints
  int* bcnt      = row_start + N_NODES + 1;
  int* bstart    = bcnt + NBUCK;
  int* bcursor   = bstart + NBUCK + 1;
  char* scratch  = (char*)(bcursor + NBUCK);
  scratch = (char*)(((uintptr_t)scratch + 15) & ~(uintptr_t)15);
  unsigned* binned     = (unsigned*)scratch;                    // 6.4 MB
  unsigned short* ms1  = (unsigned short*)scratch;              // 12.8 MB (after bfine)
  unsigned short* ms2  = xbf;                                   // after lin1
  unsigned short* Wcat1 = (unsigned short*)(scratch + featB);
  unsigned short* Wcat2 = Wcat1 + 64 * 128;
  float* b2p            = (float*)(Wcat2 + 48 * 128);

  const int NCHUNK = (N_EDGES + 4095) / 4096;   // 391 chunks
  const int AGG_BLOCKS = (N_NODES + 3) / 4;     // one wave per node
  const int LIN_BLOCKS = ((N_NODES / 16) + 3) / 4;

  // ---- bf16 caches ----
  cvt_kernel<<<(N_NODES * D / 8 + 255) / 256, 256, 0, stream>>>(x, xbf, N_NODES * D / 8);
  wcvt_kernel<<<57, 256, 0, stream>>>(W1l, W1r, W2l, W2r, b2, Wcat1, Wcat2, b2p);

  // ---- build CSR (two-level bucket sort) ----
  hipMemsetAsync(bcnt, 0, NBUCK * sizeof(int), stream);
  bhist_kernel<<<NCHUNK, 256, 0, stream>>>(dst, bcnt, N_EDGES);
  bscan_kernel<<<1, 256, 0, stream>>>(bcnt, bstart, bcursor, N_EDGES);
  bscatter_kernel<<<NCHUNK, 256, 0, stream>>>(src, dst, bcursor, binned, N_EDGES);
  bfine_kernel<<<NBUCK, 256, 0, stream>>>(binned, bstart, row_start, csr, N_NODES, N_EDGES);

  // ---- layer 1 ----
  agg_kernel<<<AGG_BLOCKS, 256, 0, stream>>>(xbf, row_start, csr, ms1, N_NODES);
  lin1_kernel<<<LIN_BLOCKS, 256, 0, stream>>>(xbf, ms1, Wcat1, b1, hbf, N_NODES);

  // ---- layer 2 ----
  agg_kernel<<<AGG_BLOCKS, 256, 0, stream>>>(hbf, row_start, csr, ms2, N_NODES);
  lin2_kernel<<<LIN_BLOCKS, 256, 0, stream>>>(hbf, ms2, Wcat2, b2p, out, N_NODES);
}